// Round 3
// baseline (8088.598 us; speedup 1.0000x reference)
//
#include <hip/hip_runtime.h>
#include <stdint.h>

#define IMGF 800.0f
#define CLIPF 4.135166556742356f

// ---------- helpers ----------
__device__ __forceinline__ uint32_t fkey(float x){
  uint32_t b = __float_as_uint(x);
  return (b & 0x80000000u) ? ~b : (b | 0x80000000u);
}

// descending bitonic sort of n (pow2) uint64 keys in LDS
__device__ void bitonic_desc(unsigned long long* k, int n, int tid, int nthr){
  for (int kk=2; kk<=n; kk<<=1){
    for (int j=kk>>1; j>0; j>>=1){
      __syncthreads();
      for (int i=tid; i<n; i+=nthr){
        int ixj = i ^ j;
        if (ixj > i){
          unsigned long long a = k[i], b = k[ixj];
          bool up = ((i & kk) == 0);
          if ((a < b) == up){ k[i]=b; k[ixj]=a; }
        }
      }
    }
  }
  __syncthreads();
}

// ---------- 0a. zero-pad input: ipad[b][c][Hp][Wp], data at [1..H][1..W] ----------
__global__ __launch_bounds__(256) void pad_input(
    const float* __restrict__ in, float* __restrict__ out, int H, int W, int Hp, int Wp){
  int idx = blockIdx.x*256 + threadIdx.x;
  int total = 2*256*Hp*Wp;
  if (idx >= total) return;
  int xp = idx % Wp; int rest = idx / Wp;
  int yp = rest % Hp; int bc = rest / Hp;
  int x = xp-1, y = yp-1;
  float v = 0.f;
  if (x>=0 && x<W && y>=0 && y<H) v = in[(size_t)bc*H*W + (size_t)y*W + x];
  out[idx] = v;
}

// ---------- 0b. repack rpn head weights: wrp2[wv][cc][20], o = wv+4j ----------
__global__ __launch_bounds__(256) void repack_heads_w(
    const float* __restrict__ wc, const float* __restrict__ wb, float* __restrict__ wrp2){
  int idx = blockIdx.x*256 + threadIdx.x;
  if (idx >= 4*256*20) return;
  int j = idx % 20; int rest = idx/20;
  int cc = rest & 255; int wv = rest >> 8;
  int o = wv + 4*j;
  float v = 0.f;
  if (j < 19 && o < 75) v = (o<15) ? wc[o*256+cc] : wb[(o-15)*256+cc];
  wrp2[idx] = v;
}

// ---------- 1. RPN conv3x3 + ReLU (padded input, 32 oc/block, 4-ic staging) ----------
__global__ __launch_bounds__(256) void conv3x3_relu2(
    const float* __restrict__ ipad, const float* __restrict__ w,
    const float* __restrict__ bias, float* __restrict__ out,
    int H, int W, int Hp, int Wp){
  const int b = blockIdx.z >> 3, ocg = blockIdx.z & 7;
  const int tx = threadIdx.x & 15, ty = threadIdx.x >> 4;
  const int ox = blockIdx.x*16 + tx, oy = blockIdx.y*16 + ty;
  __shared__ float sIn[4][18][20];
  float acc[32];
  #pragma unroll
  for (int i=0;i<32;i++) acc[i]=0.f;
  const float* inb = ipad + (size_t)b*256*Hp*Wp;
  const int y0 = blockIdx.y*16, x0 = blockIdx.x*16;  // padded-coord window origin
  for (int icb=0; icb<256; icb+=4){
    __syncthreads();
    for (int t=threadIdx.x; t<1296; t+=256){
      int pl = t/324, r = t - pl*324;
      int ry = r/18, rx = r - ry*18;
      int iy = y0+ry; if (iy > Hp-1) iy = Hp-1;   // clamps land on zero border
      int ix = x0+rx; if (ix > Wp-1) ix = Wp-1;
      sIn[pl][ry][rx] = inb[((size_t)(icb+pl)*Hp + iy)*Wp + ix];
    }
    __syncthreads();
    #pragma unroll
    for (int pl=0; pl<4; ++pl){
      float r00=sIn[pl][ty+0][tx+0], r01=sIn[pl][ty+0][tx+1], r02=sIn[pl][ty+0][tx+2];
      float r10=sIn[pl][ty+1][tx+0], r11=sIn[pl][ty+1][tx+1], r12=sIn[pl][ty+1][tx+2];
      float r20=sIn[pl][ty+2][tx+0], r21=sIn[pl][ty+2][tx+1], r22=sIn[pl][ty+2][tx+2];
      const float* wp0 = w + ((size_t)(ocg*32)*256 + (size_t)(icb+pl))*9;
      #pragma unroll
      for (int oc=0;oc<32;++oc){
        const float* wp = wp0 + (size_t)oc*2304;
        acc[oc] += r00*wp[0] + r01*wp[1] + r02*wp[2]
                 + r10*wp[3] + r11*wp[4] + r12*wp[5]
                 + r20*wp[6] + r21*wp[7] + r22*wp[8];
      }
    }
  }
  if (ox < W && oy < H){
    #pragma unroll
    for (int oc=0;oc<32;++oc){
      int o = ocg*32+oc;
      out[((size_t)b*256 + o)*H*W + (size_t)oy*W + ox] = fmaxf(acc[oc] + bias[o], 0.f);
    }
  }
}

// ---------- 2. RPN 1x1 heads (repacked weights) ----------
__global__ __launch_bounds__(256) void rpn_heads(
    const float* __restrict__ t, const float* __restrict__ wrp2,
    const float* __restrict__ bc, const float* __restrict__ bb,
    float* __restrict__ objs, float* __restrict__ dels, int HW, int lvlOff){
  int b = blockIdx.y;
  int p0 = blockIdx.x*64;
  int lane = threadIdx.x & 63;
  int wv = threadIdx.x >> 6;
  __shared__ float sh[128][64];
  float acc[19];
  #pragma unroll
  for (int j=0;j<19;j++) acc[j]=0.f;
  const float* tb = t + (size_t)b*256*HW;
  for (int half=0; half<2; ++half){
    __syncthreads();
    for (int i=threadIdx.x; i<8192; i+=256){
      int c = i>>6, px = i&63;
      int p = p0+px;
      sh[c][px] = (p<HW) ? tb[(size_t)(half*128+c)*HW + p] : 0.f;
    }
    __syncthreads();
    for (int c=0;c<128;c++){
      float v = sh[c][lane];
      int cc = half*128 + c;
      const float* wr = wrp2 + ((size_t)wv*256 + cc)*20;
      #pragma unroll
      for (int j=0;j<19;j++){
        int o = wv + 4*j;
        if (o < 75) acc[j] += v*wr[j];
      }
    }
  }
  int p = p0 + lane;
  if (p < HW){
    #pragma unroll
    for (int j=0;j<19;j++){
      int o = wv + 4*j;
      if (o < 75){
        if (o < 15){
          objs[(size_t)b*196875 + lvlOff + (size_t)p*15 + o] = acc[j] + bc[o];
        } else {
          int q = o-15;
          dels[((size_t)b*196875 + lvlOff + (size_t)p*15 + (q>>2))*4 + (q&3)] = acc[j] + bb[q];
        }
      }
    }
  }
}

// ---------- 3. feats NCHW -> position-major channel-last ----------
__global__ __launch_bounds__(256) void feat_transpose(
    const float* __restrict__ f, float* __restrict__ ft, int HW, int posOff){
  __shared__ float tile[32][33];
  int b = blockIdx.z;
  int p0 = blockIdx.x*32, c0 = blockIdx.y*32;
  int tx = threadIdx.x & 31, ty = threadIdx.x >> 5;
  #pragma unroll
  for (int i=0;i<4;i++){
    int c = c0 + ty + i*8;
    int p = p0 + tx;
    tile[ty+i*8][tx] = (p<HW) ? f[((size_t)b*256 + c)*HW + p] : 0.f;
  }
  __syncthreads();
  #pragma unroll
  for (int i=0;i<4;i++){
    int p = p0 + ty + i*8;
    int c = c0 + tx;
    if (p < HW) ft[((size_t)b*13125 + posOff + p)*256 + c] = tile[tx][ty+i*8];
  }
}

// ---------- 4. per (batch,level) exact top-500 + decode ----------
__global__ __launch_bounds__(1024) void rpn_topk_decode(
    const float* __restrict__ objs, const float* __restrict__ dels,
    float* __restrict__ lvl_boxes, float* __restrict__ lvl_scores){
  const int lvl = blockIdx.x, b = blockIdx.y;
  const int Ns[3]   = {150000,37500,9375};
  const int Offs[3] = {0,150000,187500};
  const int Wl[3]   = {100,50,25};
  const float strid[3] = {8.f,16.f,32.f};
  const int N = Ns[lvl];
  const float* sc = objs + (size_t)b*196875 + Offs[lvl];
  __shared__ uint32_t hist[2048];
  __shared__ uint32_t sPrefix;
  __shared__ int sKrem;
  __shared__ int sCnt;
  __shared__ unsigned long long keys[2048];
  int tid = threadIdx.x;
  if (tid==0){ sKrem=500; sPrefix=0; }
  for (int i=tid;i<2048;i+=1024) hist[i]=0u;
  __syncthreads();
  for (int i=tid;i<N;i+=1024){ uint32_t u=fkey(sc[i]); atomicAdd(&hist[u>>21],1u); }
  __syncthreads();
  if (tid==0){
    int cum=0, K=sKrem;
    for (int i=2047;i>=0;i--){ int c=(int)hist[i]; if (cum+c>=K){ sPrefix=(uint32_t)i<<21; sKrem=K-cum; break;} cum+=c; }
  }
  __syncthreads();
  uint32_t pref1 = sPrefix;
  for (int i=tid;i<2048;i+=1024) hist[i]=0u;
  __syncthreads();
  for (int i=tid;i<N;i+=1024){ uint32_t u=fkey(sc[i]); if ((u & 0xFFE00000u)==pref1) atomicAdd(&hist[(u>>10)&0x7FFu],1u); }
  __syncthreads();
  if (tid==0){
    int cum=0, K=sKrem;
    for (int i=2047;i>=0;i--){ int c=(int)hist[i]; if (cum+c>=K){ sPrefix=pref1|((uint32_t)i<<10); sKrem=K-cum; break;} cum+=c; }
  }
  __syncthreads();
  uint32_t pref2 = sPrefix;
  for (int i=tid;i<2048;i+=1024) hist[i]=0u;
  __syncthreads();
  for (int i=tid;i<N;i+=1024){ uint32_t u=fkey(sc[i]); if ((u & 0xFFFFFC00u)==pref2) atomicAdd(&hist[u & 0x3FFu],1u); }
  __syncthreads();
  if (tid==0){
    int cum=0, K=sKrem;
    for (int i=1023;i>=0;i--){ int c=(int)hist[i]; if (cum+c>=K){ sPrefix=pref2|(uint32_t)i; break;} cum+=c; }
    sCnt=0;
  }
  __syncthreads();
  uint32_t T = sPrefix;
  for (int i=tid;i<N;i+=1024){
    uint32_t u=fkey(sc[i]);
    if (u>=T){ int k=atomicAdd(&sCnt,1); if (k<2048) keys[k]=((unsigned long long)u<<32)|(uint32_t)(~(uint32_t)i); }
  }
  __syncthreads();
  int m = sCnt; if (m>2048) m=2048;
  int n = 512; while (n<m) n<<=1;
  for (int i=tid;i<n;i+=1024) if (i>=m) keys[i]=0ull;
  __syncthreads();
  bitonic_desc(keys, n, tid, 1024);
  if (tid < 500){
    unsigned long long key = keys[tid];
    uint32_t idx = ~(uint32_t)(key & 0xFFFFFFFFull);
    float score = sc[idx];
    int p = idx/15, a = idx - p*15;
    int W = Wl[lvl];
    int hh = p / W, ww = p - hh*W;
    int r5 = a/5, s5 = a - r5*5;
    const float ratios[3] = {0.5f,1.0f,2.0f};
    const float scales[5] = {32.f,64.f,128.f,256.f,512.f};
    float hr = sqrtf(ratios[r5]); float wr = 1.0f/hr;
    float wsz = wr*scales[s5], hsz = hr*scales[s5];
    float sx = (float)ww*strid[lvl], sy = (float)hh*strid[lvl];
    float ax1 = sx - 0.5f*wsz, ay1 = sy - 0.5f*hsz;
    float ax2 = sx + 0.5f*wsz, ay2 = sy + 0.5f*hsz;
    const float* dl = dels + ((size_t)b*196875 + Offs[lvl] + idx)*4;
    float bw = ax2-ax1, bh = ay2-ay1;
    float cx = ax1 + 0.5f*bw, cy = ay1 + 0.5f*bh;
    float dx = dl[0], dy = dl[1];
    float dw = fminf(dl[2], CLIPF), dh = fminf(dl[3], CLIPF);
    float pcx = dx*bw + cx, pcy = dy*bh + cy;
    float pw = expf(dw)*bw, ph = expf(dh)*bh;
    float x1 = fminf(fmaxf(pcx - 0.5f*pw, 0.f), IMGF);
    float y1 = fminf(fmaxf(pcy - 0.5f*ph, 0.f), IMGF);
    float x2 = fminf(fmaxf(pcx + 0.5f*pw, 0.f), IMGF);
    float y2 = fminf(fmaxf(pcy + 0.5f*ph, 0.f), IMGF);
    int oidx = b*1500 + lvl*500 + tid;
    lvl_boxes[oidx*4+0]=x1; lvl_boxes[oidx*4+1]=y1;
    lvl_boxes[oidx*4+2]=x2; lvl_boxes[oidx*4+3]=y2;
    bool valid = (x2-x1 >= 1e-3f) && (y2-y1 >= 1e-3f);
    lvl_scores[oidx] = valid ? score : -1e9f;
  }
}

// ---------- 5a. NMS: sort by score, emit sorted offset-boxes + order ----------
__global__ __launch_bounds__(1024) void nms_sort(
    const float* __restrict__ lvl_boxes, const float* __restrict__ lvl_scores,
    float* __restrict__ snb, int* __restrict__ sorder){
  int b = blockIdx.x, tid = threadIdx.x;
  __shared__ unsigned long long keys[2048];
  const float* ls = lvl_scores + (size_t)b*1500;
  const float* lb = lvl_boxes + (size_t)b*1500*4;
  for (int i=tid;i<2048;i+=1024)
    keys[i] = (i<1500) ? (((unsigned long long)fkey(ls[i])<<32)|(uint32_t)(~(uint32_t)i)) : 0ull;
  __syncthreads();
  bitonic_desc(keys, 2048, tid, 1024);
  for (int r=tid;r<1536;r+=1024){
    if (r < 1500){
      int idx = (int)(~(uint32_t)keys[r]);
      sorder[(size_t)b*1536 + r] = idx;
      float offv = (float)(idx/500) * (IMGF + 16.0f);
      float* pp = snb + ((size_t)b*1536 + r)*4;
      pp[0]=lb[idx*4+0]+offv; pp[1]=lb[idx*4+1]+offv;
      pp[2]=lb[idx*4+2]+offv; pp[3]=lb[idx*4+3]+offv;
    } else {
      sorder[(size_t)b*1536 + r] = 0;
      float* pp = snb + ((size_t)b*1536 + r)*4;
      pp[0]=pp[1]=pp[2]=pp[3]=0.f;
    }
  }
}

// ---------- 5b. NMS: IoU suppression bitmask matrix ----------
__global__ __launch_bounds__(256) void nms_mask(
    const float* __restrict__ snb, unsigned long long* __restrict__ masks){
  int b = blockIdx.y;
  int i0 = blockIdx.x*64;
  __shared__ float sbx[1536][4];
  for (int t=threadIdx.x; t<1536*4; t+=256)
    sbx[t>>2][t&3] = snb[(size_t)b*1536*4 + t];
  __syncthreads();
  int il = threadIdx.x >> 2;
  int wq = threadIdx.x & 3;
  int i = i0 + il;
  float ax1=sbx[i][0], ay1=sbx[i][1], ax2=sbx[i][2], ay2=sbx[i][3];
  float aa=(ax2-ax1)*(ay2-ay1);
  #pragma unroll
  for (int wofs=0; wofs<6; ++wofs){
    int w = wq*6 + wofs;
    unsigned long long m = 0ull;
    if (i < 1500){
      for (int jj=0; jj<64; ++jj){
        int j = w*64 + jj;
        if (j > i && j < 1500){
          float bx1=sbx[j][0],by1=sbx[j][1],bx2=sbx[j][2],by2=sbx[j][3];
          float ab=(bx2-bx1)*(by2-by1);
          float lx=fmaxf(ax1,bx1), ly=fmaxf(ay1,by1);
          float rx=fminf(ax2,bx2), ry=fminf(ay2,by2);
          float iw=fmaxf(rx-lx,0.f), ih=fmaxf(ry-ly,0.f);
          float inter=iw*ih;
          if (inter/(aa+ab-inter+1e-9f) > 0.7f) m |= (1ull<<jj);
        }
      }
    }
    masks[((size_t)b*1536 + i)*24 + w] = m;
  }
}

// ---------- 5c. NMS: serial bitmask scan + final top-512 gather ----------
__global__ __launch_bounds__(1024) void nms_scan_final(
    const unsigned long long* __restrict__ masks, const int* __restrict__ sorder,
    const float* __restrict__ lvl_boxes, const float* __restrict__ lvl_scores,
    float* __restrict__ props){
  int b = blockIdx.x, tid = threadIdx.x;
  __shared__ unsigned long long cm[128][24];
  __shared__ volatile unsigned long long keepw[24];
  __shared__ unsigned char korig[1536];
  __shared__ unsigned long long keys[2048];
  if (tid < 24) keepw[tid] = (tid==23) ? ((1ull<<28)-1ull) : ~0ull;
  for (int c=0; c<12; ++c){
    __syncthreads();
    for (int t=tid; t<128*24; t+=1024)
      cm[t/24][t%24] = masks[((size_t)b*1536 + c*128)*24 + t];
    __syncthreads();
    if (tid < 24){
      int lim = (c==11) ? 84 : 128;
      for (int il=0; il<lim; ++il){
        int i = c*128 + il;
        unsigned long long kw = keepw[i>>6];
        if ((kw>>(i&63)) & 1ull) keepw[tid] &= ~cm[il][tid];
      }
    }
  }
  __syncthreads();
  for (int r=tid; r<1500; r+=1024){
    unsigned long long kw = keepw[r>>6];
    korig[sorder[(size_t)b*1536 + r]] = (unsigned char)((kw>>(r&63)) & 1ull);
  }
  __syncthreads();
  const float* ls = lvl_scores + (size_t)b*1500;
  const float* lb = lvl_boxes + (size_t)b*1500*4;
  for (int i=tid;i<2048;i+=1024){
    if (i<1500){
      float s = korig[i] ? ls[i] : -1e9f;
      keys[i] = ((unsigned long long)fkey(s)<<32)|(uint32_t)(~(uint32_t)i);
    } else keys[i]=0ull;
  }
  __syncthreads();
  bitonic_desc(keys, 2048, tid, 1024);
  for (int j=tid;j<512;j+=1024){
    int idx = (int)(~(uint32_t)keys[j]);
    float* pp = props + ((size_t)b*512 + j)*4;
    pp[0]=lb[idx*4+0]; pp[1]=lb[idx*4+1]; pp[2]=lb[idx*4+2]; pp[3]=lb[idx*4+3];
  }
}

// ---------- 6. ROI align ----------
__global__ __launch_bounds__(256) void roi_align(
    const float* __restrict__ featT, const float* __restrict__ props,
    float* __restrict__ roiX){
  int blk = blockIdx.x;
  int b = blk >> 9, n = blk & 511;
  const float* box = props + ((size_t)b*512 + n)*4;
  float x1=box[0], y1=box[1], x2=box[2], y2=box[3];
  float area = fmaxf(x2-x1,0.f)*fmaxf(y2-y1,0.f);
  float kf = floorf(4.0f + log2f(sqrtf(area)/224.0f + 1e-6f));
  kf = fminf(fmaxf(kf, 3.f), 5.f);
  int lvl = (int)kf - 3;
  const int Wl[3] = {100,50,25};
  const int posOff[3] = {0,10000,12500};
  const float strid[3] = {8.f,16.f,32.f};
  float scl = 1.0f/strid[lvl];
  float hw = (float)Wl[lvl];
  float rx1 = x1*scl, ry1 = y1*scl;
  float rw = fmaxf(x2*scl - rx1, 1.0f), rh = fmaxf(y2*scl - ry1, 1.0f);
  float bw = rw/7.0f, bh = rh/7.0f;
  __shared__ int sIdx[196][4];
  __shared__ float sW[196][4];
  int t = threadIdx.x;
  if (t < 196){
    int bin = t>>2, s = t&3;
    int py = bin/7, px = bin - py*7;
    int sy = s>>1, sx = s&1;
    float sgy = ((float)sy + 0.5f)*0.5f, sgx = ((float)sx + 0.5f)*0.5f;
    float Y = ry1 + ((float)py + sgy)*bh;
    float X = rx1 + ((float)px + sgx)*bw;
    Y = fminf(fmaxf(Y,0.f), hw-1.0f);
    X = fminf(fmaxf(X,0.f), hw-1.0f);
    float y0 = floorf(Y), x0 = floorf(X);
    float ly = Y-y0, lx = X-x0;
    int y0i=(int)y0, x0i=(int)x0;
    int hi = Wl[lvl]-1;
    int y1i = (y0i+1<hi)?(y0i+1):hi;
    int x1i = (x0i+1<hi)?(x0i+1):hi;
    int W = Wl[lvl];
    int base = b*13125 + posOff[lvl];
    sIdx[t][0] = (base + y0i*W + x0i)*256;
    sIdx[t][1] = (base + y0i*W + x1i)*256;
    sIdx[t][2] = (base + y1i*W + x0i)*256;
    sIdx[t][3] = (base + y1i*W + x1i)*256;
    sW[t][0]=(1.f-ly)*(1.f-lx); sW[t][1]=(1.f-ly)*lx;
    sW[t][2]=ly*(1.f-lx);       sW[t][3]=ly*lx;
  }
  __syncthreads();
  int c = t;
  float* orow = roiX + ((size_t)b*512 + n)*12544 + (size_t)c*49;
  for (int bin=0;bin<49;bin++){
    float acc = 0.f;
    #pragma unroll
    for (int s=0;s<4;s++){
      int tt = bin*4+s;
      acc += sW[tt][0]*featT[sIdx[tt][0]+c] + sW[tt][1]*featT[sIdx[tt][1]+c]
           + sW[tt][2]*featT[sIdx[tt][2]+c] + sW[tt][3]*featT[sIdx[tt][3]+c];
    }
    orow[bin] = acc*0.25f;
  }
}

// ---------- 7. split-K GEMM: A via LDS (swizzled, double-buffered), B via s_load ----------
// tile M=128 (64 lanes x 2 rows), N=64 (4 waves x 16 cols), K-step 32.
__global__ __launch_bounds__(256) void gemm_sload(
    const float* __restrict__ Am, const float* __restrict__ Bm,
    float* __restrict__ part, int M, int N, int K, int KC){
  __shared__ float As[2][32*128];
  const int tid = threadIdx.x;
  const int wv = tid>>6, lane = tid&63;
  const int bn = blockIdx.x*64, bm = blockIdx.y*128, kz = blockIdx.z;
  const int k0 = kz*KC; const int T = KC/32;
  const int srow = tid>>3, skf = (tid&7)*4;
  float4 rg[4];
  float acc0[16], acc1[16];
  #pragma unroll
  for (int c=0;c<16;c++){ acc0[c]=0.f; acc1[c]=0.f; }
  const int m0 = 2*lane, m1 = 2*lane+1;
  const int s0 = (m0>>1)&31, s1 = (m1>>1)&31;   // == lane&31 for both

  // prologue: load + store step 0
  #pragma unroll
  for (int rr=0; rr<4; ++rr)
    rg[rr] = *reinterpret_cast<const float4*>(&Am[(size_t)(bm + srow + 32*rr)*K + k0 + skf]);
  #pragma unroll
  for (int rr=0; rr<4; ++rr){
    int row = srow + 32*rr;
    int sw = (row>>1)&31;
    float* a = &As[0][row*32];
    a[(skf+0)^sw]=rg[rr].x; a[(skf+1)^sw]=rg[rr].y; a[(skf+2)^sw]=rg[rr].z; a[(skf+3)^sw]=rg[rr].w;
  }
  __syncthreads();
  int cur = 0;
  for (int t=0; t<T; ++t){
    const int kb = k0 + t*32;
    if (t+1 < T){
      #pragma unroll
      for (int rr=0; rr<4; ++rr)
        rg[rr] = *reinterpret_cast<const float4*>(&Am[(size_t)(bm + srow + 32*rr)*K + kb + 32 + skf]);
    }
    const float* bK = Bm + (size_t)kb*N + bn + wv*16;
    const float* a0base = &As[cur][m0*32];
    const float* a1base = &As[cur][m1*32];
    #pragma unroll 4
    for (int kk=0; kk<32; ++kk){
      float a0 = a0base[kk ^ s0];
      float a1 = a1base[kk ^ s1];
      const float* bp = bK + (size_t)kk*N;
      #pragma unroll
      for (int c=0;c<16;c++){
        float bv = bp[c];
        acc0[c] += a0*bv;
        acc1[c] += a1*bv;
      }
    }
    if (t+1 < T){
      #pragma unroll
      for (int rr=0; rr<4; ++rr){
        int row = srow + 32*rr;
        int sw = (row>>1)&31;
        float* a = &As[cur^1][row*32];
        a[(skf+0)^sw]=rg[rr].x; a[(skf+1)^sw]=rg[rr].y; a[(skf+2)^sw]=rg[rr].z; a[(skf+3)^sw]=rg[rr].w;
      }
      __syncthreads();
      cur ^= 1;
    }
  }
  float* pz = part + (size_t)kz*M*N;
  #pragma unroll
  for (int c4=0;c4<4;c4++){
    *reinterpret_cast<float4*>(&pz[(size_t)(bm+m0)*N + bn + wv*16 + c4*4]) =
        make_float4(acc0[c4*4],acc0[c4*4+1],acc0[c4*4+2],acc0[c4*4+3]);
    *reinterpret_cast<float4*>(&pz[(size_t)(bm+m1)*N + bn + wv*16 + c4*4]) =
        make_float4(acc1[c4*4],acc1[c4*4+1],acc1[c4*4+2],acc1[c4*4+3]);
  }
}

// reduce SPLITK=4 partials + bias (+relu). N must be pow2.
__global__ __launch_bounds__(256) void reduce_splitk(
    const float* __restrict__ part, const float* __restrict__ bias,
    float* __restrict__ out, int MN, int Nmask, int relu){
  int i4 = (blockIdx.x*256 + threadIdx.x)*4;
  if (i4 < MN){
    float4 s0 = *reinterpret_cast<const float4*>(&part[i4]);
    float4 s1 = *reinterpret_cast<const float4*>(&part[(size_t)MN + i4]);
    float4 s2 = *reinterpret_cast<const float4*>(&part[(size_t)2*MN + i4]);
    float4 s3 = *reinterpret_cast<const float4*>(&part[(size_t)3*MN + i4]);
    float4 bb = *reinterpret_cast<const float4*>(&bias[i4 & Nmask]);
    float4 r;
    r.x = s0.x+s1.x+s2.x+s3.x+bb.x;
    r.y = s0.y+s1.y+s2.y+s3.y+bb.y;
    r.z = s0.z+s1.z+s2.z+s3.z+bb.z;
    r.w = s0.w+s1.w+s2.w+s3.w+bb.w;
    if (relu){ r.x=fmaxf(r.x,0.f); r.y=fmaxf(r.y,0.f); r.z=fmaxf(r.z,0.f); r.w=fmaxf(r.w,0.f); }
    *reinterpret_cast<float4*>(&out[i4]) = r;
  }
}

// ---------- 8. cls/box heads: wave-per-output shuffle reduce ----------
__global__ __launch_bounds__(256) void fc_heads(
    const float* __restrict__ x,
    const float* __restrict__ wcls, const float* __restrict__ bcls,
    const float* __restrict__ wbox, const float* __restrict__ bbox,
    float* __restrict__ cls, float* __restrict__ box){
  int row = blockIdx.x, tid = threadIdx.x;
  __shared__ float xs[1024];
  *reinterpret_cast<float4*>(&xs[tid*4]) =
      *reinterpret_cast<const float4*>(&x[(size_t)row*1024 + tid*4]);
  __syncthreads();
  int w = tid >> 6, lane = tid & 63;
  for (int o=w; o<10; o+=4){
    float p = 0.f;
    if (o < 2){
      for (int k=lane;k<1024;k+=64) p += xs[k]*wcls[(size_t)k*2 + o];
    } else {
      int q = o-2;
      for (int k=lane;k<1024;k+=64) p += xs[k]*wbox[(size_t)k*8 + q];
    }
    #pragma unroll
    for (int off=32; off>0; off>>=1) p += __shfl_down(p, off);
    if (lane==0){
      if (o<2) cls[(size_t)row*2 + o] = p + bcls[o];
      else     box[(size_t)row*8 + (o-2)] = p + bbox[o-2];
    }
  }
}

// ---------- 9. per-batch postprocess (bitmask NMS in LDS) ----------
__global__ __launch_bounds__(1024) void postprocess_kernel(
    const float* __restrict__ cls, const float* __restrict__ boxd,
    const float* __restrict__ props, float* __restrict__ out){
  int b = blockIdx.x, tid = threadIdx.x;
  __shared__ float pb[512][4];
  __shared__ float sraw[512];
  __shared__ float s2a[512];
  __shared__ unsigned long long keys[512];
  __shared__ unsigned short order_[512];
  __shared__ unsigned char kval[512];
  __shared__ unsigned char korig[512];
  __shared__ unsigned long long pm[512][8];
  __shared__ volatile unsigned long long kw2[8];
  if (tid < 8) kw2[tid] = ~0ull;
  if (tid < 512){
    int r = b*512 + tid;
    float c0 = cls[(size_t)r*2+0], c1 = cls[(size_t)r*2+1];
    float mx = fmaxf(c0,c1);
    float e0 = expf(c0-mx), e1 = expf(c1-mx);
    float s = e1/(e0+e1);
    const float* pr = props + (size_t)r*4;
    float x1=pr[0], y1=pr[1], x2=pr[2], y2=pr[3];
    float w = x2-x1, h = y2-y1;
    float cx = x1 + 0.5f*w, cy = y1 + 0.5f*h;
    const float* dl = boxd + (size_t)r*8 + 4;
    float dx = dl[0]/10.f, dy = dl[1]/10.f;
    float dw = fminf(dl[2]/5.f, CLIPF), dh = fminf(dl[3]/5.f, CLIPF);
    float pcx = dx*w + cx, pcy = dy*h + cy;
    float pw = expf(dw)*w, ph = expf(dh)*h;
    float bx1 = fminf(fmaxf(pcx-0.5f*pw,0.f), IMGF);
    float by1 = fminf(fmaxf(pcy-0.5f*ph,0.f), IMGF);
    float bx2 = fminf(fmaxf(pcx+0.5f*pw,0.f), IMGF);
    float by2 = fminf(fmaxf(pcy+0.5f*ph,0.f), IMGF);
    pb[tid][0]=bx1; pb[tid][1]=by1; pb[tid][2]=bx2; pb[tid][3]=by2;
    bool valid = (s > 0.05f) && (bx2-bx1 >= 1e-2f) && (by2-by1 >= 1e-2f);
    sraw[tid]=s; kval[tid] = valid ? 1 : 0;
    float sm = valid ? s : -1e9f;
    keys[tid] = ((unsigned long long)fkey(sm)<<32) | (uint32_t)(~(uint32_t)tid);
  }
  __syncthreads();
  bitonic_desc(keys, 512, tid, 1024);
  if (tid < 512) order_[tid] = (unsigned short)(~(uint32_t)keys[tid]);
  __syncthreads();
  {
    int r = tid >> 1;
    int oi = order_[r];
    float ax1=pb[oi][0],ay1=pb[oi][1],ax2=pb[oi][2],ay2=pb[oi][3];
    float aa=(ax2-ax1)*(ay2-ay1);
    #pragma unroll
    for (int wo=0; wo<4; ++wo){
      int w = (tid&1)*4 + wo;
      unsigned long long m = 0ull;
      for (int jj=0;jj<64;jj++){
        int j = w*64 + jj;
        if (j > r){
          int oj = order_[j];
          float bx1=pb[oj][0],by1=pb[oj][1],bx2=pb[oj][2],by2=pb[oj][3];
          float ab=(bx2-bx1)*(by2-by1);
          float lx=fmaxf(ax1,bx1), ly=fmaxf(ay1,by1);
          float rx=fminf(ax2,bx2), ry=fminf(ay2,by2);
          float iw=fmaxf(rx-lx,0.f), ih=fmaxf(ry-ly,0.f);
          float inter=iw*ih;
          if (inter/(aa+ab-inter+1e-9f) > 0.5f) m |= (1ull<<jj);
        }
      }
      pm[r][w] = m;
    }
  }
  __syncthreads();
  if (tid < 8){
    for (int i=0;i<512;i++){
      unsigned long long kwv = kw2[i>>6];
      if ((kwv>>(i&63)) & 1ull) kw2[tid] &= ~pm[i][tid];
    }
  }
  __syncthreads();
  if (tid < 512){
    unsigned long long kwv = kw2[tid>>6];
    korig[order_[tid]] = (unsigned char)((kwv>>(tid&63)) & 1ull);
  }
  __syncthreads();
  if (tid < 512){
    float s2 = (korig[tid] && kval[tid]) ? sraw[tid] : 0.f;
    s2a[tid] = s2;
    keys[tid] = ((unsigned long long)fkey(s2)<<32) | (uint32_t)(~(uint32_t)tid);
  }
  __syncthreads();
  bitonic_desc(keys, 512, tid, 1024);
  if (tid < 100){
    uint32_t idx = ~(uint32_t)keys[tid];
    float ts = s2a[idx];
    float ok = (ts > 0.f) ? 1.f : 0.f;
    float* op = out + ((size_t)b*100 + tid)*6;
    op[0]=pb[idx][0]*ok; op[1]=pb[idx][1]*ok;
    op[2]=pb[idx][2]*ok; op[3]=pb[idx][3]*ok;
    op[4]=ts; op[5]=ok;
  }
}

// ---------- host launch ----------
extern "C" void kernel_launch(void* const* d_in, const int* in_sizes, int n_in,
                              void* d_out, int out_size, void* d_ws, size_t ws_size,
                              hipStream_t stream){
  (void)in_sizes; (void)n_in; (void)out_size; (void)ws_size;
  const float* feat[3] = {(const float*)d_in[0], (const float*)d_in[1], (const float*)d_in[2]};
  const float* rpn_conv_w = (const float*)d_in[3];
  const float* rpn_conv_b = (const float*)d_in[4];
  const float* rpn_cls_w  = (const float*)d_in[5];
  const float* rpn_cls_b  = (const float*)d_in[6];
  const float* rpn_box_w  = (const float*)d_in[7];
  const float* rpn_box_b  = (const float*)d_in[8];
  const float* fc1_w = (const float*)d_in[9];
  const float* fc1_b = (const float*)d_in[10];
  const float* fc2_w = (const float*)d_in[11];
  const float* fc2_b = (const float*)d_in[12];
  const float* cls_w = (const float*)d_in[13];
  const float* cls_b = (const float*)d_in[14];
  const float* box_w = (const float*)d_in[15];
  const float* box_b = (const float*)d_in[16];

  float* ws = (float*)d_ws;
  // region A [0 .. 6,720,000): featT (live transpose..roi_align) / fc stage after
  float* featT = ws;
  float* fc1o  = ws;                        // 1,048,576
  float* fc2o  = ws + 1048576;              // 1,048,576
  float* clsb  = ws + 2097152;              //     2,048
  float* boxb  = ws + 2099200;              //     8,192
  float* parts = ws + 2107392;              // 4,194,304 -> ends 6,301,696
  float* props = ws + 6720000;              //     4,096
  // region C [6,724,096 ..): roiX (roi_align..fc1), earlier aliased by RPN temps
  float* roiX  = ws + 6724096;              // 12,845,056
  float* t_buf      = roiX;                 // 5,120,000
  float* objs       = roiX + 5120000;       //   393,750
  float* dels       = roiX + 5513750;       // 1,575,000
  float* lvl_boxes  = roiX + 7088750;       //    12,000
  float* lvl_scores = roiX + 7100750;       //     3,000
  float* nms_snb    = roiX + 7103750;       //    12,288
  int*   nms_order  = (int*)(roiX + 7116038);
  unsigned long long* nms_masks = (unsigned long long*)(roiX + 7119110); // ends 7,266,566
  float* padbuf = roiX + 7270400;           // max 5,431,296 -> ends 12,701,696
  float* wrp2   = roiX + 12710016;          //    20,480 -> ends 12,730,496

  const int Hs[3]    = {100,50,25};
  const int Hps[3]   = {102,52,27};
  const int Wps[3]   = {104,56,32};
  const int HWs[3]   = {10000,2500,625};
  const int lvlOff[3]= {0,150000,187500};
  const int posOff[3]= {0,10000,12500};

  repack_heads_w<<<80, 256, 0, stream>>>(rpn_cls_w, rpn_box_w, wrp2);

  for (int l=0;l<3;l++){
    int H = Hs[l], Hp = Hps[l], Wp = Wps[l];
    int padtot = 2*256*Hp*Wp;
    pad_input<<<(padtot+255)/256, 256, 0, stream>>>(feat[l], padbuf, H, H, Hp, Wp);
    int nt = (H+15)/16;
    conv3x3_relu2<<<dim3(nt,nt,16), 256, 0, stream>>>(padbuf, rpn_conv_w, rpn_conv_b, t_buf, H, H, Hp, Wp);
    dim3 gh((HWs[l]+63)/64, 2);
    rpn_heads<<<gh, 256, 0, stream>>>(t_buf, wrp2, rpn_cls_b, rpn_box_b,
                                      objs, dels, HWs[l], lvlOff[l]);
    dim3 gt((HWs[l]+31)/32, 8, 2);
    feat_transpose<<<gt, 256, 0, stream>>>(feat[l], featT, HWs[l], posOff[l]);
  }
  rpn_topk_decode<<<dim3(3,2), 1024, 0, stream>>>(objs, dels, lvl_boxes, lvl_scores);
  nms_sort<<<2, 1024, 0, stream>>>(lvl_boxes, lvl_scores, nms_snb, nms_order);
  nms_mask<<<dim3(24,2), 256, 0, stream>>>(nms_snb, nms_masks);
  nms_scan_final<<<2, 1024, 0, stream>>>(nms_masks, nms_order, lvl_boxes, lvl_scores, props);
  roi_align<<<1024, 256, 0, stream>>>(featT, props, roiX);
  // fc1: [1024,12544] x [12544,1024], split-K=4 (KC=3136, T=98)
  gemm_sload<<<dim3(16,8,4), 256, 0, stream>>>(roiX, fc1_w, parts, 1024, 1024, 12544, 3136);
  reduce_splitk<<<1024, 256, 0, stream>>>(parts, fc1_b, fc1o, 1024*1024, 1023, 1);
  // fc2: [1024,1024] x [1024,1024], split-K=4 (KC=256, T=8)
  gemm_sload<<<dim3(16,8,4), 256, 0, stream>>>(fc1o, fc2_w, parts, 1024, 1024, 1024, 256);
  reduce_splitk<<<1024, 256, 0, stream>>>(parts, fc2_b, fc2o, 1024*1024, 1023, 1);
  fc_heads<<<1024, 256, 0, stream>>>(fc2o, cls_w, cls_b, box_w, box_b, clsb, boxb);
  postprocess_kernel<<<2, 1024, 0, stream>>>(clsb, boxb, props, (float*)d_out);
}

// Round 4
// 3234.640 us; speedup vs baseline: 2.5006x; 2.5006x over previous
//
#include <hip/hip_runtime.h>
#include <stdint.h>

#define IMGF 800.0f
#define CLIPF 4.135166556742356f

// ---------- helpers ----------
__device__ __forceinline__ uint32_t fkey(float x){
  uint32_t b = __float_as_uint(x);
  return (b & 0x80000000u) ? ~b : (b | 0x80000000u);
}

// descending bitonic sort of n (pow2) uint64 keys in LDS
__device__ void bitonic_desc(unsigned long long* k, int n, int tid, int nthr){
  for (int kk=2; kk<=n; kk<<=1){
    for (int j=kk>>1; j>0; j>>=1){
      __syncthreads();
      for (int i=tid; i<n; i+=nthr){
        int ixj = i ^ j;
        if (ixj > i){
          unsigned long long a = k[i], b = k[ixj];
          bool up = ((i & kk) == 0);
          if ((a < b) == up){ k[i]=b; k[ixj]=a; }
        }
      }
    }
  }
  __syncthreads();
}

// ---------- 0a. repack conv weights: w2[ic][oc][9] = w[oc][ic][9] ----------
__global__ __launch_bounds__(256) void repack_conv_w(
    const float* __restrict__ w, float* __restrict__ w2){
  int idx = blockIdx.x*256 + threadIdx.x;
  if (idx >= 589824) return;            // 256*256*9
  int k = idx % 9; int rest = idx / 9;
  int oc = rest & 255; int ic = rest >> 8;
  w2[idx] = w[((size_t)oc*256 + ic)*9 + k];
}

// ---------- 0b. repack rpn head weights: wrp2[wv][cc][20], o = wv+4j ----------
__global__ __launch_bounds__(256) void repack_heads_w(
    const float* __restrict__ wc, const float* __restrict__ wb, float* __restrict__ wrp2){
  int idx = blockIdx.x*256 + threadIdx.x;
  if (idx >= 4*256*20) return;
  int j = idx % 20; int rest = idx/20;
  int cc = rest & 255; int wv = rest >> 8;
  int o = wv + 4*j;
  float v = 0.f;
  if (j < 19 && o < 75) v = (o<15) ? wc[o*256+cc] : wb[(o-15)*256+cc];
  wrp2[idx] = v;
}

// ---------- 1. RPN conv3x3 + ReLU, all levels in one launch ----------
// block = 16x16 spatial x 16 oc x BOTH batch images. 256 threads.
// weights repacked [ic][oc][9]: per (pl) the scalar set is 144 contiguous
// floats (R2-proven size); each 9-float group feeds 18 FMAs (2 batches).
__global__ __launch_bounds__(256) void conv3x3_all(
    const float* __restrict__ f0, const float* __restrict__ f1, const float* __restrict__ f2,
    const float* __restrict__ w2, const float* __restrict__ bias,
    float* __restrict__ t0, float* __restrict__ t1, float* __restrict__ t2){
  const int bid = blockIdx.x;
  const int lvl = (bid < 784) ? 0 : (bid < 1040 ? 1 : 2);
  const int basev[3] = {0, 784, 1040};
  const int nxv[3]   = {7, 4, 2};
  const int Hv[3]    = {100, 50, 25};
  const float* fin = (lvl==0) ? f0 : (lvl==1 ? f1 : f2);
  float* tout      = (lvl==0) ? t0 : (lvl==1 ? t1 : t2);
  const int tloc = bid - basev[lvl];
  const int ocg = tloc & 15;
  const int txy = tloc >> 4;
  const int nx = nxv[lvl];
  const int bx = txy % nx, by = txy / nx;
  const int H = Hv[lvl];
  const int HW = H*H;
  const int tx = threadIdx.x & 15, ty = threadIdx.x >> 4;
  const int ox = bx*16 + tx, oy = by*16 + ty;
  const int x0 = bx*16 - 1, y0 = by*16 - 1;

  __shared__ float sIn[2][2][18][20];
  float acc0[16], acc1[16];
  #pragma unroll
  for (int i=0;i<16;i++){ acc0[i]=0.f; acc1[i]=0.f; }

  for (int icb=0; icb<256; icb+=2){
    __syncthreads();
    // stage 2 ic x 2 batches x 18x18 (clamped to zero outside)
    for (int t=threadIdx.x; t<1296; t+=256){
      int pl = t/648; int r = t - pl*648;
      int bb = r/324; int rr = r - bb*324;
      int ry = rr/18, rx = rr - ry*18;
      int iy = y0+ry, ix = x0+rx;
      float v = 0.f;
      if (iy>=0 && iy<H && ix>=0 && ix<H)
        v = fin[((size_t)(bb*256 + icb+pl)*H + iy)*H + ix];
      sIn[pl][bb][ry][rx] = v;
    }
    __syncthreads();
    #pragma unroll
    for (int pl=0; pl<2; ++pl){
      float i0[9], i1[9];
      #pragma unroll
      for (int dy=0; dy<3; ++dy)
        #pragma unroll
        for (int dx=0; dx<3; ++dx){
          i0[dy*3+dx] = sIn[pl][0][ty+dy][tx+dx];
          i1[dy*3+dx] = sIn[pl][1][ty+dy][tx+dx];
        }
      const float* wp0 = w2 + ((size_t)(icb+pl)*256 + ocg*16)*9;
      #pragma unroll
      for (int oc=0; oc<16; ++oc){
        const float* wp = wp0 + oc*9;
        float w0=wp[0], w1=wp[1], w2_=wp[2], w3=wp[3], w4=wp[4],
              w5=wp[5], w6=wp[6], w7=wp[7], w8=wp[8];
        acc0[oc] += w0*i0[0] + w1*i0[1] + w2_*i0[2]
                  + w3*i0[3] + w4*i0[4] + w5*i0[5]
                  + w6*i0[6] + w7*i0[7] + w8*i0[8];
        acc1[oc] += w0*i1[0] + w1*i1[1] + w2_*i1[2]
                  + w3*i1[3] + w4*i1[4] + w5*i1[5]
                  + w6*i1[6] + w7*i1[7] + w8*i1[8];
      }
    }
  }
  if (ox < H && oy < H){
    #pragma unroll
    for (int oc=0; oc<16; ++oc){
      int o = ocg*16 + oc;
      float bz = bias[o];
      tout[((size_t)o)*HW + (size_t)oy*H + ox]            = fmaxf(acc0[oc] + bz, 0.f);
      tout[((size_t)(256 + o))*HW + (size_t)oy*H + ox]    = fmaxf(acc1[oc] + bz, 0.f);
    }
  }
}

// ---------- 2. RPN 1x1 heads (repacked weights) ----------
__global__ __launch_bounds__(256) void rpn_heads(
    const float* __restrict__ t, const float* __restrict__ wrp2,
    const float* __restrict__ bc, const float* __restrict__ bb,
    float* __restrict__ objs, float* __restrict__ dels, int HW, int lvlOff){
  int b = blockIdx.y;
  int p0 = blockIdx.x*64;
  int lane = threadIdx.x & 63;
  int wv = threadIdx.x >> 6;
  __shared__ float sh[128][64];
  float acc[19];
  #pragma unroll
  for (int j=0;j<19;j++) acc[j]=0.f;
  const float* tb = t + (size_t)b*256*HW;
  for (int half=0; half<2; ++half){
    __syncthreads();
    for (int i=threadIdx.x; i<8192; i+=256){
      int c = i>>6, px = i&63;
      int p = p0+px;
      sh[c][px] = (p<HW) ? tb[(size_t)(half*128+c)*HW + p] : 0.f;
    }
    __syncthreads();
    for (int c=0;c<128;c++){
      float v = sh[c][lane];
      int cc = half*128 + c;
      const float* wr = wrp2 + ((size_t)wv*256 + cc)*20;
      #pragma unroll
      for (int j=0;j<19;j++){
        int o = wv + 4*j;
        if (o < 75) acc[j] += v*wr[j];
      }
    }
  }
  int p = p0 + lane;
  if (p < HW){
    #pragma unroll
    for (int j=0;j<19;j++){
      int o = wv + 4*j;
      if (o < 75){
        if (o < 15){
          objs[(size_t)b*196875 + lvlOff + (size_t)p*15 + o] = acc[j] + bc[o];
        } else {
          int q = o-15;
          dels[((size_t)b*196875 + lvlOff + (size_t)p*15 + (q>>2))*4 + (q&3)] = acc[j] + bb[q];
        }
      }
    }
  }
}

// ---------- 3. feats NCHW -> position-major channel-last ----------
__global__ __launch_bounds__(256) void feat_transpose(
    const float* __restrict__ f, float* __restrict__ ft, int HW, int posOff){
  __shared__ float tile[32][33];
  int b = blockIdx.z;
  int p0 = blockIdx.x*32, c0 = blockIdx.y*32;
  int tx = threadIdx.x & 31, ty = threadIdx.x >> 5;
  #pragma unroll
  for (int i=0;i<4;i++){
    int c = c0 + ty + i*8;
    int p = p0 + tx;
    tile[ty+i*8][tx] = (p<HW) ? f[((size_t)b*256 + c)*HW + p] : 0.f;
  }
  __syncthreads();
  #pragma unroll
  for (int i=0;i<4;i++){
    int p = p0 + ty + i*8;
    int c = c0 + tx;
    if (p < HW) ft[((size_t)b*13125 + posOff + p)*256 + c] = tile[tx][ty+i*8];
  }
}

// ---------- 4. per (batch,level) exact top-500 + decode ----------
__global__ __launch_bounds__(1024) void rpn_topk_decode(
    const float* __restrict__ objs, const float* __restrict__ dels,
    float* __restrict__ lvl_boxes, float* __restrict__ lvl_scores){
  const int lvl = blockIdx.x, b = blockIdx.y;
  const int Ns[3]   = {150000,37500,9375};
  const int Offs[3] = {0,150000,187500};
  const int Wl[3]   = {100,50,25};
  const float strid[3] = {8.f,16.f,32.f};
  const int N = Ns[lvl];
  const float* sc = objs + (size_t)b*196875 + Offs[lvl];
  __shared__ uint32_t hist[2048];
  __shared__ uint32_t sPrefix;
  __shared__ int sKrem;
  __shared__ int sCnt;
  __shared__ unsigned long long keys[2048];
  int tid = threadIdx.x;
  if (tid==0){ sKrem=500; sPrefix=0; }
  for (int i=tid;i<2048;i+=1024) hist[i]=0u;
  __syncthreads();
  for (int i=tid;i<N;i+=1024){ uint32_t u=fkey(sc[i]); atomicAdd(&hist[u>>21],1u); }
  __syncthreads();
  if (tid==0){
    int cum=0, K=sKrem;
    for (int i=2047;i>=0;i--){ int c=(int)hist[i]; if (cum+c>=K){ sPrefix=(uint32_t)i<<21; sKrem=K-cum; break;} cum+=c; }
  }
  __syncthreads();
  uint32_t pref1 = sPrefix;
  for (int i=tid;i<2048;i+=1024) hist[i]=0u;
  __syncthreads();
  for (int i=tid;i<N;i+=1024){ uint32_t u=fkey(sc[i]); if ((u & 0xFFE00000u)==pref1) atomicAdd(&hist[(u>>10)&0x7FFu],1u); }
  __syncthreads();
  if (tid==0){
    int cum=0, K=sKrem;
    for (int i=2047;i>=0;i--){ int c=(int)hist[i]; if (cum+c>=K){ sPrefix=pref1|((uint32_t)i<<10); sKrem=K-cum; break;} cum+=c; }
  }
  __syncthreads();
  uint32_t pref2 = sPrefix;
  for (int i=tid;i<2048;i+=1024) hist[i]=0u;
  __syncthreads();
  for (int i=tid;i<N;i+=1024){ uint32_t u=fkey(sc[i]); if ((u & 0xFFFFFC00u)==pref2) atomicAdd(&hist[u & 0x3FFu],1u); }
  __syncthreads();
  if (tid==0){
    int cum=0, K=sKrem;
    for (int i=1023;i>=0;i--){ int c=(int)hist[i]; if (cum+c>=K){ sPrefix=pref2|(uint32_t)i; break;} cum+=c; }
    sCnt=0;
  }
  __syncthreads();
  uint32_t T = sPrefix;
  for (int i=tid;i<N;i+=1024){
    uint32_t u=fkey(sc[i]);
    if (u>=T){ int k=atomicAdd(&sCnt,1); if (k<2048) keys[k]=((unsigned long long)u<<32)|(uint32_t)(~(uint32_t)i); }
  }
  __syncthreads();
  int m = sCnt; if (m>2048) m=2048;
  int n = 512; while (n<m) n<<=1;
  for (int i=tid;i<n;i+=1024) if (i>=m) keys[i]=0ull;
  __syncthreads();
  bitonic_desc(keys, n, tid, 1024);
  if (tid < 500){
    unsigned long long key = keys[tid];
    uint32_t idx = ~(uint32_t)(key & 0xFFFFFFFFull);
    float score = sc[idx];
    int p = idx/15, a = idx - p*15;
    int W = Wl[lvl];
    int hh = p / W, ww = p - hh*W;
    int r5 = a/5, s5 = a - r5*5;
    const float ratios[3] = {0.5f,1.0f,2.0f};
    const float scales[5] = {32.f,64.f,128.f,256.f,512.f};
    float hr = sqrtf(ratios[r5]); float wr = 1.0f/hr;
    float wsz = wr*scales[s5], hsz = hr*scales[s5];
    float sx = (float)ww*strid[lvl], sy = (float)hh*strid[lvl];
    float ax1 = sx - 0.5f*wsz, ay1 = sy - 0.5f*hsz;
    float ax2 = sx + 0.5f*wsz, ay2 = sy + 0.5f*hsz;
    const float* dl = dels + ((size_t)b*196875 + Offs[lvl] + idx)*4;
    float bw = ax2-ax1, bh = ay2-ay1;
    float cx = ax1 + 0.5f*bw, cy = ay1 + 0.5f*bh;
    float dx = dl[0], dy = dl[1];
    float dw = fminf(dl[2], CLIPF), dh = fminf(dl[3], CLIPF);
    float pcx = dx*bw + cx, pcy = dy*bh + cy;
    float pw = expf(dw)*bw, ph = expf(dh)*bh;
    float x1 = fminf(fmaxf(pcx - 0.5f*pw, 0.f), IMGF);
    float y1 = fminf(fmaxf(pcy - 0.5f*ph, 0.f), IMGF);
    float x2 = fminf(fmaxf(pcx + 0.5f*pw, 0.f), IMGF);
    float y2 = fminf(fmaxf(pcy + 0.5f*ph, 0.f), IMGF);
    int oidx = b*1500 + lvl*500 + tid;
    lvl_boxes[oidx*4+0]=x1; lvl_boxes[oidx*4+1]=y1;
    lvl_boxes[oidx*4+2]=x2; lvl_boxes[oidx*4+3]=y2;
    bool valid = (x2-x1 >= 1e-3f) && (y2-y1 >= 1e-3f);
    lvl_scores[oidx] = valid ? score : -1e9f;
  }
}

// ---------- 5a. NMS: sort by score, emit sorted offset-boxes + order ----------
__global__ __launch_bounds__(1024) void nms_sort(
    const float* __restrict__ lvl_boxes, const float* __restrict__ lvl_scores,
    float* __restrict__ snb, int* __restrict__ sorder){
  int b = blockIdx.x, tid = threadIdx.x;
  __shared__ unsigned long long keys[2048];
  const float* ls = lvl_scores + (size_t)b*1500;
  const float* lb = lvl_boxes + (size_t)b*1500*4;
  for (int i=tid;i<2048;i+=1024)
    keys[i] = (i<1500) ? (((unsigned long long)fkey(ls[i])<<32)|(uint32_t)(~(uint32_t)i)) : 0ull;
  __syncthreads();
  bitonic_desc(keys, 2048, tid, 1024);
  for (int r=tid;r<1536;r+=1024){
    if (r < 1500){
      int idx = (int)(~(uint32_t)keys[r]);
      sorder[(size_t)b*1536 + r] = idx;
      float offv = (float)(idx/500) * (IMGF + 16.0f);
      float* pp = snb + ((size_t)b*1536 + r)*4;
      pp[0]=lb[idx*4+0]+offv; pp[1]=lb[idx*4+1]+offv;
      pp[2]=lb[idx*4+2]+offv; pp[3]=lb[idx*4+3]+offv;
    } else {
      sorder[(size_t)b*1536 + r] = 0;
      float* pp = snb + ((size_t)b*1536 + r)*4;
      pp[0]=pp[1]=pp[2]=pp[3]=0.f;
    }
  }
}

// ---------- 5b. NMS: IoU suppression bitmask matrix ----------
__global__ __launch_bounds__(256) void nms_mask(
    const float* __restrict__ snb, unsigned long long* __restrict__ masks){
  int b = blockIdx.y;
  int i0 = blockIdx.x*64;
  __shared__ float sbx[1536][4];
  for (int t=threadIdx.x; t<1536*4; t+=256)
    sbx[t>>2][t&3] = snb[(size_t)b*1536*4 + t];
  __syncthreads();
  int il = threadIdx.x >> 2;
  int wq = threadIdx.x & 3;
  int i = i0 + il;
  float ax1=sbx[i][0], ay1=sbx[i][1], ax2=sbx[i][2], ay2=sbx[i][3];
  float aa=(ax2-ax1)*(ay2-ay1);
  #pragma unroll
  for (int wofs=0; wofs<6; ++wofs){
    int w = wq*6 + wofs;
    unsigned long long m = 0ull;
    if (i < 1500){
      for (int jj=0; jj<64; ++jj){
        int j = w*64 + jj;
        if (j > i && j < 1500){
          float bx1=sbx[j][0],by1=sbx[j][1],bx2=sbx[j][2],by2=sbx[j][3];
          float ab=(bx2-bx1)*(by2-by1);
          float lx=fmaxf(ax1,bx1), ly=fmaxf(ay1,by1);
          float rx=fminf(ax2,bx2), ry=fminf(ay2,by2);
          float iw=fmaxf(rx-lx,0.f), ih=fmaxf(ry-ly,0.f);
          float inter=iw*ih;
          if (inter/(aa+ab-inter+1e-9f) > 0.7f) m |= (1ull<<jj);
        }
      }
    }
    masks[((size_t)b*1536 + i)*24 + w] = m;
  }
}

// ---------- 5c. NMS: serial bitmask scan + final top-512 gather ----------
__global__ __launch_bounds__(1024) void nms_scan_final(
    const unsigned long long* __restrict__ masks, const int* __restrict__ sorder,
    const float* __restrict__ lvl_boxes, const float* __restrict__ lvl_scores,
    float* __restrict__ props){
  int b = blockIdx.x, tid = threadIdx.x;
  __shared__ unsigned long long cm[128][24];
  __shared__ volatile unsigned long long keepw[24];
  __shared__ unsigned char korig[1536];
  __shared__ unsigned long long keys[2048];
  if (tid < 24) keepw[tid] = (tid==23) ? ((1ull<<28)-1ull) : ~0ull;
  for (int c=0; c<12; ++c){
    __syncthreads();
    for (int t=tid; t<128*24; t+=1024)
      cm[t/24][t%24] = masks[((size_t)b*1536 + c*128)*24 + t];
    __syncthreads();
    if (tid < 24){
      int lim = (c==11) ? 84 : 128;
      for (int il=0; il<lim; ++il){
        int i = c*128 + il;
        unsigned long long kw = keepw[i>>6];
        if ((kw>>(i&63)) & 1ull) keepw[tid] &= ~cm[il][tid];
      }
    }
  }
  __syncthreads();
  for (int r=tid; r<1500; r+=1024){
    unsigned long long kw = keepw[r>>6];
    korig[sorder[(size_t)b*1536 + r]] = (unsigned char)((kw>>(r&63)) & 1ull);
  }
  __syncthreads();
  const float* ls = lvl_scores + (size_t)b*1500;
  const float* lb = lvl_boxes + (size_t)b*1500*4;
  for (int i=tid;i<2048;i+=1024){
    if (i<1500){
      float s = korig[i] ? ls[i] : -1e9f;
      keys[i] = ((unsigned long long)fkey(s)<<32)|(uint32_t)(~(uint32_t)i);
    } else keys[i]=0ull;
  }
  __syncthreads();
  bitonic_desc(keys, 2048, tid, 1024);
  for (int j=tid;j<512;j+=1024){
    int idx = (int)(~(uint32_t)keys[j]);
    float* pp = props + ((size_t)b*512 + j)*4;
    pp[0]=lb[idx*4+0]; pp[1]=lb[idx*4+1]; pp[2]=lb[idx*4+2]; pp[3]=lb[idx*4+3];
  }
}

// ---------- 6. ROI align ----------
__global__ __launch_bounds__(256) void roi_align(
    const float* __restrict__ featT, const float* __restrict__ props,
    float* __restrict__ roiX){
  int blk = blockIdx.x;
  int b = blk >> 9, n = blk & 511;
  const float* box = props + ((size_t)b*512 + n)*4;
  float x1=box[0], y1=box[1], x2=box[2], y2=box[3];
  float area = fmaxf(x2-x1,0.f)*fmaxf(y2-y1,0.f);
  float kf = floorf(4.0f + log2f(sqrtf(area)/224.0f + 1e-6f));
  kf = fminf(fmaxf(kf, 3.f), 5.f);
  int lvl = (int)kf - 3;
  const int Wl[3] = {100,50,25};
  const int posOff[3] = {0,10000,12500};
  const float strid[3] = {8.f,16.f,32.f};
  float scl = 1.0f/strid[lvl];
  float hw = (float)Wl[lvl];
  float rx1 = x1*scl, ry1 = y1*scl;
  float rw = fmaxf(x2*scl - rx1, 1.0f), rh = fmaxf(y2*scl - ry1, 1.0f);
  float bw = rw/7.0f, bh = rh/7.0f;
  __shared__ int sIdx[196][4];
  __shared__ float sW[196][4];
  int t = threadIdx.x;
  if (t < 196){
    int bin = t>>2, s = t&3;
    int py = bin/7, px = bin - py*7;
    int sy = s>>1, sx = s&1;
    float sgy = ((float)sy + 0.5f)*0.5f, sgx = ((float)sx + 0.5f)*0.5f;
    float Y = ry1 + ((float)py + sgy)*bh;
    float X = rx1 + ((float)px + sgx)*bw;
    Y = fminf(fmaxf(Y,0.f), hw-1.0f);
    X = fminf(fmaxf(X,0.f), hw-1.0f);
    float y0 = floorf(Y), x0 = floorf(X);
    float ly = Y-y0, lx = X-x0;
    int y0i=(int)y0, x0i=(int)x0;
    int hi = Wl[lvl]-1;
    int y1i = (y0i+1<hi)?(y0i+1):hi;
    int x1i = (x0i+1<hi)?(x0i+1):hi;
    int W = Wl[lvl];
    int base = b*13125 + posOff[lvl];
    sIdx[t][0] = (base + y0i*W + x0i)*256;
    sIdx[t][1] = (base + y0i*W + x1i)*256;
    sIdx[t][2] = (base + y1i*W + x0i)*256;
    sIdx[t][3] = (base + y1i*W + x1i)*256;
    sW[t][0]=(1.f-ly)*(1.f-lx); sW[t][1]=(1.f-ly)*lx;
    sW[t][2]=ly*(1.f-lx);       sW[t][3]=ly*lx;
  }
  __syncthreads();
  int c = t;
  float* orow = roiX + ((size_t)b*512 + n)*12544 + (size_t)c*49;
  for (int bin=0;bin<49;bin++){
    float acc = 0.f;
    #pragma unroll
    for (int s=0;s<4;s++){
      int tt = bin*4+s;
      acc += sW[tt][0]*featT[sIdx[tt][0]+c] + sW[tt][1]*featT[sIdx[tt][1]+c]
           + sW[tt][2]*featT[sIdx[tt][2]+c] + sW[tt][3]*featT[sIdx[tt][3]+c];
    }
    orow[bin] = acc*0.25f;
  }
}

// ---------- 7. split-K GEMM: A via LDS (swizzled, double-buffered), B via s_load ----------
__global__ __launch_bounds__(256) void gemm_sload(
    const float* __restrict__ Am, const float* __restrict__ Bm,
    float* __restrict__ part, int M, int N, int K, int KC){
  __shared__ float As[2][32*128];
  const int tid = threadIdx.x;
  const int wv = tid>>6, lane = tid&63;
  const int bn = blockIdx.x*64, bm = blockIdx.y*128, kz = blockIdx.z;
  const int k0 = kz*KC; const int T = KC/32;
  const int srow = tid>>3, skf = (tid&7)*4;
  float4 rg[4];
  float acc0[16], acc1[16];
  #pragma unroll
  for (int c=0;c<16;c++){ acc0[c]=0.f; acc1[c]=0.f; }
  const int m0 = 2*lane, m1 = 2*lane+1;
  const int s0 = (m0>>1)&31, s1 = (m1>>1)&31;

  #pragma unroll
  for (int rr=0; rr<4; ++rr)
    rg[rr] = *reinterpret_cast<const float4*>(&Am[(size_t)(bm + srow + 32*rr)*K + k0 + skf]);
  #pragma unroll
  for (int rr=0; rr<4; ++rr){
    int row = srow + 32*rr;
    int sw = (row>>1)&31;
    float* a = &As[0][row*32];
    a[(skf+0)^sw]=rg[rr].x; a[(skf+1)^sw]=rg[rr].y; a[(skf+2)^sw]=rg[rr].z; a[(skf+3)^sw]=rg[rr].w;
  }
  __syncthreads();
  int cur = 0;
  for (int t=0; t<T; ++t){
    const int kb = k0 + t*32;
    if (t+1 < T){
      #pragma unroll
      for (int rr=0; rr<4; ++rr)
        rg[rr] = *reinterpret_cast<const float4*>(&Am[(size_t)(bm + srow + 32*rr)*K + kb + 32 + skf]);
    }
    const float* bK = Bm + (size_t)kb*N + bn + wv*16;
    const float* a0base = &As[cur][m0*32];
    const float* a1base = &As[cur][m1*32];
    #pragma unroll 4
    for (int kk=0; kk<32; ++kk){
      float a0 = a0base[kk ^ s0];
      float a1 = a1base[kk ^ s1];
      const float* bp = bK + (size_t)kk*N;
      #pragma unroll
      for (int c=0;c<16;c++){
        float bv = bp[c];
        acc0[c] += a0*bv;
        acc1[c] += a1*bv;
      }
    }
    if (t+1 < T){
      #pragma unroll
      for (int rr=0; rr<4; ++rr){
        int row = srow + 32*rr;
        int sw = (row>>1)&31;
        float* a = &As[cur^1][row*32];
        a[(skf+0)^sw]=rg[rr].x; a[(skf+1)^sw]=rg[rr].y; a[(skf+2)^sw]=rg[rr].z; a[(skf+3)^sw]=rg[rr].w;
      }
      __syncthreads();
      cur ^= 1;
    }
  }
  float* pz = part + (size_t)kz*M*N;
  #pragma unroll
  for (int c4=0;c4<4;c4++){
    *reinterpret_cast<float4*>(&pz[(size_t)(bm+m0)*N + bn + wv*16 + c4*4]) =
        make_float4(acc0[c4*4],acc0[c4*4+1],acc0[c4*4+2],acc0[c4*4+3]);
    *reinterpret_cast<float4*>(&pz[(size_t)(bm+m1)*N + bn + wv*16 + c4*4]) =
        make_float4(acc1[c4*4],acc1[c4*4+1],acc1[c4*4+2],acc1[c4*4+3]);
  }
}

// reduce SPLITK=4 partials + bias (+relu). N must be pow2.
__global__ __launch_bounds__(256) void reduce_splitk(
    const float* __restrict__ part, const float* __restrict__ bias,
    float* __restrict__ out, int MN, int Nmask, int relu){
  int i4 = (blockIdx.x*256 + threadIdx.x)*4;
  if (i4 < MN){
    float4 s0 = *reinterpret_cast<const float4*>(&part[i4]);
    float4 s1 = *reinterpret_cast<const float4*>(&part[(size_t)MN + i4]);
    float4 s2 = *reinterpret_cast<const float4*>(&part[(size_t)2*MN + i4]);
    float4 s3 = *reinterpret_cast<const float4*>(&part[(size_t)3*MN + i4]);
    float4 bb = *reinterpret_cast<const float4*>(&bias[i4 & Nmask]);
    float4 r;
    r.x = s0.x+s1.x+s2.x+s3.x+bb.x;
    r.y = s0.y+s1.y+s2.y+s3.y+bb.y;
    r.z = s0.z+s1.z+s2.z+s3.z+bb.z;
    r.w = s0.w+s1.w+s2.w+s3.w+bb.w;
    if (relu){ r.x=fmaxf(r.x,0.f); r.y=fmaxf(r.y,0.f); r.z=fmaxf(r.z,0.f); r.w=fmaxf(r.w,0.f); }
    *reinterpret_cast<float4*>(&out[i4]) = r;
  }
}

// ---------- 8. cls/box heads: wave-per-output shuffle reduce ----------
__global__ __launch_bounds__(256) void fc_heads(
    const float* __restrict__ x,
    const float* __restrict__ wcls, const float* __restrict__ bcls,
    const float* __restrict__ wbox, const float* __restrict__ bbox,
    float* __restrict__ cls, float* __restrict__ box){
  int row = blockIdx.x, tid = threadIdx.x;
  __shared__ float xs[1024];
  *reinterpret_cast<float4*>(&xs[tid*4]) =
      *reinterpret_cast<const float4*>(&x[(size_t)row*1024 + tid*4]);
  __syncthreads();
  int w = tid >> 6, lane = tid & 63;
  for (int o=w; o<10; o+=4){
    float p = 0.f;
    if (o < 2){
      for (int k=lane;k<1024;k+=64) p += xs[k]*wcls[(size_t)k*2 + o];
    } else {
      int q = o-2;
      for (int k=lane;k<1024;k+=64) p += xs[k]*wbox[(size_t)k*8 + q];
    }
    #pragma unroll
    for (int off=32; off>0; off>>=1) p += __shfl_down(p, off);
    if (lane==0){
      if (o<2) cls[(size_t)row*2 + o] = p + bcls[o];
      else     box[(size_t)row*8 + (o-2)] = p + bbox[o-2];
    }
  }
}

// ---------- 9. per-batch postprocess (bitmask NMS in LDS) ----------
__global__ __launch_bounds__(1024) void postprocess_kernel(
    const float* __restrict__ cls, const float* __restrict__ boxd,
    const float* __restrict__ props, float* __restrict__ out){
  int b = blockIdx.x, tid = threadIdx.x;
  __shared__ float pb[512][4];
  __shared__ float sraw[512];
  __shared__ float s2a[512];
  __shared__ unsigned long long keys[512];
  __shared__ unsigned short order_[512];
  __shared__ unsigned char kval[512];
  __shared__ unsigned char korig[512];
  __shared__ unsigned long long pm[512][8];
  __shared__ volatile unsigned long long kw2[8];
  if (tid < 8) kw2[tid] = ~0ull;
  if (tid < 512){
    int r = b*512 + tid;
    float c0 = cls[(size_t)r*2+0], c1 = cls[(size_t)r*2+1];
    float mx = fmaxf(c0,c1);
    float e0 = expf(c0-mx), e1 = expf(c1-mx);
    float s = e1/(e0+e1);
    const float* pr = props + (size_t)r*4;
    float x1=pr[0], y1=pr[1], x2=pr[2], y2=pr[3];
    float w = x2-x1, h = y2-y1;
    float cx = x1 + 0.5f*w, cy = y1 + 0.5f*h;
    const float* dl = boxd + (size_t)r*8 + 4;
    float dx = dl[0]/10.f, dy = dl[1]/10.f;
    float dw = fminf(dl[2]/5.f, CLIPF), dh = fminf(dl[3]/5.f, CLIPF);
    float pcx = dx*w + cx, pcy = dy*h + cy;
    float pw = expf(dw)*w, ph = expf(dh)*h;
    float bx1 = fminf(fmaxf(pcx-0.5f*pw,0.f), IMGF);
    float by1 = fminf(fmaxf(pcy-0.5f*ph,0.f), IMGF);
    float bx2 = fminf(fmaxf(pcx+0.5f*pw,0.f), IMGF);
    float by2 = fminf(fmaxf(pcy+0.5f*ph,0.f), IMGF);
    pb[tid][0]=bx1; pb[tid][1]=by1; pb[tid][2]=bx2; pb[tid][3]=by2;
    bool valid = (s > 0.05f) && (bx2-bx1 >= 1e-2f) && (by2-by1 >= 1e-2f);
    sraw[tid]=s; kval[tid] = valid ? 1 : 0;
    float sm = valid ? s : -1e9f;
    keys[tid] = ((unsigned long long)fkey(sm)<<32) | (uint32_t)(~(uint32_t)tid);
  }
  __syncthreads();
  bitonic_desc(keys, 512, tid, 1024);
  if (tid < 512) order_[tid] = (unsigned short)(~(uint32_t)keys[tid]);
  __syncthreads();
  {
    int r = tid >> 1;
    int oi = order_[r];
    float ax1=pb[oi][0],ay1=pb[oi][1],ax2=pb[oi][2],ay2=pb[oi][3];
    float aa=(ax2-ax1)*(ay2-ay1);
    #pragma unroll
    for (int wo=0; wo<4; ++wo){
      int w = (tid&1)*4 + wo;
      unsigned long long m = 0ull;
      for (int jj=0;jj<64;jj++){
        int j = w*64 + jj;
        if (j > r){
          int oj = order_[j];
          float bx1=pb[oj][0],by1=pb[oj][1],bx2=pb[oj][2],by2=pb[oj][3];
          float ab=(bx2-bx1)*(by2-by1);
          float lx=fmaxf(ax1,bx1), ly=fmaxf(ay1,by1);
          float rx=fminf(ax2,bx2), ry=fminf(ay2,by2);
          float iw=fmaxf(rx-lx,0.f), ih=fmaxf(ry-ly,0.f);
          float inter=iw*ih;
          if (inter/(aa+ab-inter+1e-9f) > 0.5f) m |= (1ull<<jj);
        }
      }
      pm[r][w] = m;
    }
  }
  __syncthreads();
  if (tid < 8){
    for (int i=0;i<512;i++){
      unsigned long long kwv = kw2[i>>6];
      if ((kwv>>(i&63)) & 1ull) kw2[tid] &= ~pm[i][tid];
    }
  }
  __syncthreads();
  if (tid < 512){
    unsigned long long kwv = kw2[tid>>6];
    korig[order_[tid]] = (unsigned char)((kwv>>(tid&63)) & 1ull);
  }
  __syncthreads();
  if (tid < 512){
    float s2 = (korig[tid] && kval[tid]) ? sraw[tid] : 0.f;
    s2a[tid] = s2;
    keys[tid] = ((unsigned long long)fkey(s2)<<32) | (uint32_t)(~(uint32_t)tid);
  }
  __syncthreads();
  bitonic_desc(keys, 512, tid, 1024);
  if (tid < 100){
    uint32_t idx = ~(uint32_t)keys[tid];
    float ts = s2a[idx];
    float ok = (ts > 0.f) ? 1.f : 0.f;
    float* op = out + ((size_t)b*100 + tid)*6;
    op[0]=pb[idx][0]*ok; op[1]=pb[idx][1]*ok;
    op[2]=pb[idx][2]*ok; op[3]=pb[idx][3]*ok;
    op[4]=ts; op[5]=ok;
  }
}

// ---------- host launch ----------
extern "C" void kernel_launch(void* const* d_in, const int* in_sizes, int n_in,
                              void* d_out, int out_size, void* d_ws, size_t ws_size,
                              hipStream_t stream){
  (void)in_sizes; (void)n_in; (void)out_size; (void)ws_size;
  const float* feat[3] = {(const float*)d_in[0], (const float*)d_in[1], (const float*)d_in[2]};
  const float* rpn_conv_w = (const float*)d_in[3];
  const float* rpn_conv_b = (const float*)d_in[4];
  const float* rpn_cls_w  = (const float*)d_in[5];
  const float* rpn_cls_b  = (const float*)d_in[6];
  const float* rpn_box_w  = (const float*)d_in[7];
  const float* rpn_box_b  = (const float*)d_in[8];
  const float* fc1_w = (const float*)d_in[9];
  const float* fc1_b = (const float*)d_in[10];
  const float* fc2_w = (const float*)d_in[11];
  const float* fc2_b = (const float*)d_in[12];
  const float* cls_w = (const float*)d_in[13];
  const float* cls_b = (const float*)d_in[14];
  const float* box_w = (const float*)d_in[15];
  const float* box_b = (const float*)d_in[16];

  float* ws = (float*)d_ws;
  // region A [0 .. 6,720,000): featT (live transpose..roi_align) / fc stage after
  float* featT = ws;
  float* fc1o  = ws;                        // 1,048,576
  float* fc2o  = ws + 1048576;              // 1,048,576
  float* clsb  = ws + 2097152;              //     2,048
  float* boxb  = ws + 2099200;              //     8,192
  float* parts = ws + 2107392;              // 4,194,304 -> ends 6,301,696
  float* props = ws + 6720000;              //     4,096
  // region C [6,724,096 ..): roiX (roi_align..fc1), earlier aliased by RPN temps
  float* roiX  = ws + 6724096;              // 12,845,056
  float* t0 = roiX;                         // 5,120,000
  float* t1 = roiX + 5120000;               // 1,280,000
  float* t2 = roiX + 6400000;               //   320,000
  float* objs       = roiX + 6720000;       //   393,750
  float* dels       = roiX + 7113750;       // 1,575,000
  float* lvl_boxes  = roiX + 8688750;       //    12,000
  float* lvl_scores = roiX + 8700750;       //     3,000
  float* nms_snb    = roiX + 8703750;       //    12,288
  int*   nms_order  = (int*)(roiX + 8716038);       //  3,072 ints
  unsigned long long* nms_masks = (unsigned long long*)(roiX + 8719110); // 147,456 floats
  float* wrp2  = roiX + 8866568;            //    20,480
  float* w2    = roiX + 8887048;            //   589,824 -> ends 9,476,872 (< 12,845,056)

  const int HWs[3]   = {10000,2500,625};
  const int lvlOff[3]= {0,150000,187500};
  const int posOff[3]= {0,10000,12500};

  repack_heads_w<<<80, 256, 0, stream>>>(rpn_cls_w, rpn_box_w, wrp2);
  repack_conv_w<<<2304, 256, 0, stream>>>(rpn_conv_w, w2);

  for (int l=0;l<3;l++){
    dim3 gt((HWs[l]+31)/32, 8, 2);
    feat_transpose<<<gt, 256, 0, stream>>>(feat[l], featT, HWs[l], posOff[l]);
  }
  // merged conv: 784 (L0) + 256 (L1) + 64 (L2) blocks
  conv3x3_all<<<1104, 256, 0, stream>>>(feat[0], feat[1], feat[2], w2, rpn_conv_b, t0, t1, t2);
  float* tl[3] = {t0, t1, t2};
  for (int l=0;l<3;l++){
    dim3 gh((HWs[l]+63)/64, 2);
    rpn_heads<<<gh, 256, 0, stream>>>(tl[l], wrp2, rpn_cls_b, rpn_box_b,
                                      objs, dels, HWs[l], lvlOff[l]);
  }
  rpn_topk_decode<<<dim3(3,2), 1024, 0, stream>>>(objs, dels, lvl_boxes, lvl_scores);
  nms_sort<<<2, 1024, 0, stream>>>(lvl_boxes, lvl_scores, nms_snb, nms_order);
  nms_mask<<<dim3(24,2), 256, 0, stream>>>(nms_snb, nms_masks);
  nms_scan_final<<<2, 1024, 0, stream>>>(nms_masks, nms_order, lvl_boxes, lvl_scores, props);
  roi_align<<<1024, 256, 0, stream>>>(featT, props, roiX);
  // fc1: [1024,12544] x [12544,1024], split-K=4 (KC=3136, T=98)
  gemm_sload<<<dim3(16,8,4), 256, 0, stream>>>(roiX, fc1_w, parts, 1024, 1024, 12544, 3136);
  reduce_splitk<<<1024, 256, 0, stream>>>(parts, fc1_b, fc1o, 1024*1024, 1023, 1);
  // fc2: [1024,1024] x [1024,1024], split-K=4 (KC=256, T=8)
  gemm_sload<<<dim3(16,8,4), 256, 0, stream>>>(fc1o, fc2_w, parts, 1024, 1024, 1024, 256);
  reduce_splitk<<<1024, 256, 0, stream>>>(parts, fc2_b, fc2o, 1024*1024, 1023, 1);
  fc_heads<<<1024, 256, 0, stream>>>(fc2o, cls_w, cls_b, box_w, box_b, clsb, boxb);
  postprocess_kernel<<<2, 1024, 0, stream>>>(clsb, boxb, props, (float*)d_out);
}

// Round 5
// 2619.631 us; speedup vs baseline: 3.0877x; 1.2348x over previous
//
#include <hip/hip_runtime.h>
#include <stdint.h>

#define IMGF 800.0f
#define CLIPF 4.135166556742356f

// ---------- helpers ----------
__device__ __forceinline__ uint32_t fkey(float x){
  uint32_t b = __float_as_uint(x);
  return (b & 0x80000000u) ? ~b : (b | 0x80000000u);
}

// descending bitonic sort of n (pow2) uint64 keys in LDS
__device__ void bitonic_desc(unsigned long long* k, int n, int tid, int nthr){
  for (int kk=2; kk<=n; kk<<=1){
    for (int j=kk>>1; j>0; j>>=1){
      __syncthreads();
      for (int i=tid; i<n; i+=nthr){
        int ixj = i ^ j;
        if (ixj > i){
          unsigned long long a = k[i], b = k[ixj];
          bool up = ((i & kk) == 0);
          if ((a < b) == up){ k[i]=b; k[ixj]=a; }
        }
      }
    }
  }
  __syncthreads();
}

// ---------- 0a. repack conv weights: w2[ic][oc][9] = w[oc][ic][9] ----------
__global__ __launch_bounds__(256) void repack_conv_w(
    const float* __restrict__ w, float* __restrict__ w2){
  int idx = blockIdx.x*256 + threadIdx.x;
  if (idx >= 589824) return;            // 256*256*9
  int k = idx % 9; int rest = idx / 9;
  int oc = rest & 255; int ic = rest >> 8;
  w2[idx] = w[((size_t)oc*256 + ic)*9 + k];
}

// ---------- 0b. repack rpn head weights: wrp2[wv][cc][20], o = wv+4j ----------
__global__ __launch_bounds__(256) void repack_heads_w(
    const float* __restrict__ wc, const float* __restrict__ wb, float* __restrict__ wrp2){
  int idx = blockIdx.x*256 + threadIdx.x;
  if (idx >= 4*256*20) return;
  int j = idx % 20; int rest = idx/20;
  int cc = rest & 255; int wv = rest >> 8;
  int o = wv + 4*j;
  float v = 0.f;
  if (j < 19 && o < 75) v = (o<15) ? wc[o*256+cc] : wb[(o-15)*256+cc];
  wrp2[idx] = v;
}

// ---------- 1. RPN conv3x3 + ReLU, all levels in one launch ----------
__global__ __launch_bounds__(256) void conv3x3_all(
    const float* __restrict__ f0, const float* __restrict__ f1, const float* __restrict__ f2,
    const float* __restrict__ w2, const float* __restrict__ bias,
    float* __restrict__ t0, float* __restrict__ t1, float* __restrict__ t2){
  const int bid = blockIdx.x;
  const int lvl = (bid < 784) ? 0 : (bid < 1040 ? 1 : 2);
  const int basev[3] = {0, 784, 1040};
  const int nxv[3]   = {7, 4, 2};
  const int Hv[3]    = {100, 50, 25};
  const float* fin = (lvl==0) ? f0 : (lvl==1 ? f1 : f2);
  float* tout      = (lvl==0) ? t0 : (lvl==1 ? t1 : t2);
  const int tloc = bid - basev[lvl];
  const int ocg = tloc & 15;
  const int txy = tloc >> 4;
  const int nx = nxv[lvl];
  const int bx = txy % nx, by = txy / nx;
  const int H = Hv[lvl];
  const int HW = H*H;
  const int tx = threadIdx.x & 15, ty = threadIdx.x >> 4;
  const int ox = bx*16 + tx, oy = by*16 + ty;
  const int x0 = bx*16 - 1, y0 = by*16 - 1;

  __shared__ float sIn[2][2][18][20];
  float acc0[16], acc1[16];
  #pragma unroll
  for (int i=0;i<16;i++){ acc0[i]=0.f; acc1[i]=0.f; }

  for (int icb=0; icb<256; icb+=2){
    __syncthreads();
    for (int t=threadIdx.x; t<1296; t+=256){
      int pl = t/648; int r = t - pl*648;
      int bb = r/324; int rr = r - bb*324;
      int ry = rr/18, rx = rr - ry*18;
      int iy = y0+ry, ix = x0+rx;
      float v = 0.f;
      if (iy>=0 && iy<H && ix>=0 && ix<H)
        v = fin[((size_t)(bb*256 + icb+pl)*H + iy)*H + ix];
      sIn[pl][bb][ry][rx] = v;
    }
    __syncthreads();
    #pragma unroll
    for (int pl=0; pl<2; ++pl){
      float i0[9], i1[9];
      #pragma unroll
      for (int dy=0; dy<3; ++dy)
        #pragma unroll
        for (int dx=0; dx<3; ++dx){
          i0[dy*3+dx] = sIn[pl][0][ty+dy][tx+dx];
          i1[dy*3+dx] = sIn[pl][1][ty+dy][tx+dx];
        }
      const float* wp0 = w2 + ((size_t)(icb+pl)*256 + ocg*16)*9;
      #pragma unroll
      for (int oc=0; oc<16; ++oc){
        const float* wp = wp0 + oc*9;
        float w0=wp[0], w1=wp[1], w2_=wp[2], w3=wp[3], w4=wp[4],
              w5=wp[5], w6=wp[6], w7=wp[7], w8=wp[8];
        acc0[oc] += w0*i0[0] + w1*i0[1] + w2_*i0[2]
                  + w3*i0[3] + w4*i0[4] + w5*i0[5]
                  + w6*i0[6] + w7*i0[7] + w8*i0[8];
        acc1[oc] += w0*i1[0] + w1*i1[1] + w2_*i1[2]
                  + w3*i1[3] + w4*i1[4] + w5*i1[5]
                  + w6*i1[6] + w7*i1[7] + w8*i1[8];
      }
    }
  }
  if (ox < H && oy < H){
    #pragma unroll
    for (int oc=0; oc<16; ++oc){
      int o = ocg*16 + oc;
      float bz = bias[o];
      tout[((size_t)o)*HW + (size_t)oy*H + ox]            = fmaxf(acc0[oc] + bz, 0.f);
      tout[((size_t)(256 + o))*HW + (size_t)oy*H + ox]    = fmaxf(acc1[oc] + bz, 0.f);
    }
  }
}

// ---------- 2. RPN 1x1 heads (repacked weights) ----------
__global__ __launch_bounds__(256) void rpn_heads(
    const float* __restrict__ t, const float* __restrict__ wrp2,
    const float* __restrict__ bc, const float* __restrict__ bb,
    float* __restrict__ objs, float* __restrict__ dels, int HW, int lvlOff){
  int b = blockIdx.y;
  int p0 = blockIdx.x*64;
  int lane = threadIdx.x & 63;
  int wv = threadIdx.x >> 6;
  __shared__ float sh[128][64];
  float acc[19];
  #pragma unroll
  for (int j=0;j<19;j++) acc[j]=0.f;
  const float* tb = t + (size_t)b*256*HW;
  for (int half=0; half<2; ++half){
    __syncthreads();
    for (int i=threadIdx.x; i<8192; i+=256){
      int c = i>>6, px = i&63;
      int p = p0+px;
      sh[c][px] = (p<HW) ? tb[(size_t)(half*128+c)*HW + p] : 0.f;
    }
    __syncthreads();
    for (int c=0;c<128;c++){
      float v = sh[c][lane];
      int cc = half*128 + c;
      const float* wr = wrp2 + ((size_t)wv*256 + cc)*20;
      #pragma unroll
      for (int j=0;j<19;j++){
        int o = wv + 4*j;
        if (o < 75) acc[j] += v*wr[j];
      }
    }
  }
  int p = p0 + lane;
  if (p < HW){
    #pragma unroll
    for (int j=0;j<19;j++){
      int o = wv + 4*j;
      if (o < 75){
        if (o < 15){
          objs[(size_t)b*196875 + lvlOff + (size_t)p*15 + o] = acc[j] + bc[o];
        } else {
          int q = o-15;
          dels[((size_t)b*196875 + lvlOff + (size_t)p*15 + (q>>2))*4 + (q&3)] = acc[j] + bb[q];
        }
      }
    }
  }
}

// ---------- 3. feats NCHW -> position-major channel-last ----------
__global__ __launch_bounds__(256) void feat_transpose(
    const float* __restrict__ f, float* __restrict__ ft, int HW, int posOff){
  __shared__ float tile[32][33];
  int b = blockIdx.z;
  int p0 = blockIdx.x*32, c0 = blockIdx.y*32;
  int tx = threadIdx.x & 31, ty = threadIdx.x >> 5;
  #pragma unroll
  for (int i=0;i<4;i++){
    int c = c0 + ty + i*8;
    int p = p0 + tx;
    tile[ty+i*8][tx] = (p<HW) ? f[((size_t)b*256 + c)*HW + p] : 0.f;
  }
  __syncthreads();
  #pragma unroll
  for (int i=0;i<4;i++){
    int p = p0 + ty + i*8;
    int c = c0 + tx;
    if (p < HW) ft[((size_t)b*13125 + posOff + p)*256 + c] = tile[tx][ty+i*8];
  }
}

// ---------- 4. per (batch,level) exact top-500 + decode ----------
__global__ __launch_bounds__(1024) void rpn_topk_decode(
    const float* __restrict__ objs, const float* __restrict__ dels,
    float* __restrict__ lvl_boxes, float* __restrict__ lvl_scores){
  const int lvl = blockIdx.x, b = blockIdx.y;
  const int Ns[3]   = {150000,37500,9375};
  const int Offs[3] = {0,150000,187500};
  const int Wl[3]   = {100,50,25};
  const float strid[3] = {8.f,16.f,32.f};
  const int N = Ns[lvl];
  const float* sc = objs + (size_t)b*196875 + Offs[lvl];
  __shared__ uint32_t hist[2048];
  __shared__ uint32_t sPrefix;
  __shared__ int sKrem;
  __shared__ int sCnt;
  __shared__ unsigned long long keys[2048];
  int tid = threadIdx.x;
  if (tid==0){ sKrem=500; sPrefix=0; }
  for (int i=tid;i<2048;i+=1024) hist[i]=0u;
  __syncthreads();
  for (int i=tid;i<N;i+=1024){ uint32_t u=fkey(sc[i]); atomicAdd(&hist[u>>21],1u); }
  __syncthreads();
  if (tid==0){
    int cum=0, K=sKrem;
    for (int i=2047;i>=0;i--){ int c=(int)hist[i]; if (cum+c>=K){ sPrefix=(uint32_t)i<<21; sKrem=K-cum; break;} cum+=c; }
  }
  __syncthreads();
  uint32_t pref1 = sPrefix;
  for (int i=tid;i<2048;i+=1024) hist[i]=0u;
  __syncthreads();
  for (int i=tid;i<N;i+=1024){ uint32_t u=fkey(sc[i]); if ((u & 0xFFE00000u)==pref1) atomicAdd(&hist[(u>>10)&0x7FFu],1u); }
  __syncthreads();
  if (tid==0){
    int cum=0, K=sKrem;
    for (int i=2047;i>=0;i--){ int c=(int)hist[i]; if (cum+c>=K){ sPrefix=pref1|((uint32_t)i<<10); sKrem=K-cum; break;} cum+=c; }
  }
  __syncthreads();
  uint32_t pref2 = sPrefix;
  for (int i=tid;i<2048;i+=1024) hist[i]=0u;
  __syncthreads();
  for (int i=tid;i<N;i+=1024){ uint32_t u=fkey(sc[i]); if ((u & 0xFFFFFC00u)==pref2) atomicAdd(&hist[u & 0x3FFu],1u); }
  __syncthreads();
  if (tid==0){
    int cum=0, K=sKrem;
    for (int i=1023;i>=0;i--){ int c=(int)hist[i]; if (cum+c>=K){ sPrefix=pref2|(uint32_t)i; break;} cum+=c; }
    sCnt=0;
  }
  __syncthreads();
  uint32_t T = sPrefix;
  for (int i=tid;i<N;i+=1024){
    uint32_t u=fkey(sc[i]);
    if (u>=T){ int k=atomicAdd(&sCnt,1); if (k<2048) keys[k]=((unsigned long long)u<<32)|(uint32_t)(~(uint32_t)i); }
  }
  __syncthreads();
  int m = sCnt; if (m>2048) m=2048;
  int n = 512; while (n<m) n<<=1;
  for (int i=tid;i<n;i+=1024) if (i>=m) keys[i]=0ull;
  __syncthreads();
  bitonic_desc(keys, n, tid, 1024);
  if (tid < 500){
    unsigned long long key = keys[tid];
    uint32_t idx = ~(uint32_t)(key & 0xFFFFFFFFull);
    float score = sc[idx];
    int p = idx/15, a = idx - p*15;
    int W = Wl[lvl];
    int hh = p / W, ww = p - hh*W;
    int r5 = a/5, s5 = a - r5*5;
    const float ratios[3] = {0.5f,1.0f,2.0f};
    const float scales[5] = {32.f,64.f,128.f,256.f,512.f};
    float hr = sqrtf(ratios[r5]); float wr = 1.0f/hr;
    float wsz = wr*scales[s5], hsz = hr*scales[s5];
    float sx = (float)ww*strid[lvl], sy = (float)hh*strid[lvl];
    float ax1 = sx - 0.5f*wsz, ay1 = sy - 0.5f*hsz;
    float ax2 = sx + 0.5f*wsz, ay2 = sy + 0.5f*hsz;
    const float* dl = dels + ((size_t)b*196875 + Offs[lvl] + idx)*4;
    float bw = ax2-ax1, bh = ay2-ay1;
    float cx = ax1 + 0.5f*bw, cy = ay1 + 0.5f*bh;
    float dx = dl[0], dy = dl[1];
    float dw = fminf(dl[2], CLIPF), dh = fminf(dl[3], CLIPF);
    float pcx = dx*bw + cx, pcy = dy*bh + cy;
    float pw = expf(dw)*bw, ph = expf(dh)*bh;
    float x1 = fminf(fmaxf(pcx - 0.5f*pw, 0.f), IMGF);
    float y1 = fminf(fmaxf(pcy - 0.5f*ph, 0.f), IMGF);
    float x2 = fminf(fmaxf(pcx + 0.5f*pw, 0.f), IMGF);
    float y2 = fminf(fmaxf(pcy + 0.5f*ph, 0.f), IMGF);
    int oidx = b*1500 + lvl*500 + tid;
    lvl_boxes[oidx*4+0]=x1; lvl_boxes[oidx*4+1]=y1;
    lvl_boxes[oidx*4+2]=x2; lvl_boxes[oidx*4+3]=y2;
    bool valid = (x2-x1 >= 1e-3f) && (y2-y1 >= 1e-3f);
    lvl_scores[oidx] = valid ? score : -1e9f;
  }
}

// ---------- 5a. NMS: sort by score, emit sorted offset-boxes + order ----------
__global__ __launch_bounds__(1024) void nms_sort(
    const float* __restrict__ lvl_boxes, const float* __restrict__ lvl_scores,
    float* __restrict__ snb, int* __restrict__ sorder){
  int b = blockIdx.x, tid = threadIdx.x;
  __shared__ unsigned long long keys[2048];
  const float* ls = lvl_scores + (size_t)b*1500;
  const float* lb = lvl_boxes + (size_t)b*1500*4;
  for (int i=tid;i<2048;i+=1024)
    keys[i] = (i<1500) ? (((unsigned long long)fkey(ls[i])<<32)|(uint32_t)(~(uint32_t)i)) : 0ull;
  __syncthreads();
  bitonic_desc(keys, 2048, tid, 1024);
  for (int r=tid;r<1536;r+=1024){
    if (r < 1500){
      int idx = (int)(~(uint32_t)keys[r]);
      sorder[(size_t)b*1536 + r] = idx;
      float offv = (float)(idx/500) * (IMGF + 16.0f);
      float* pp = snb + ((size_t)b*1536 + r)*4;
      pp[0]=lb[idx*4+0]+offv; pp[1]=lb[idx*4+1]+offv;
      pp[2]=lb[idx*4+2]+offv; pp[3]=lb[idx*4+3]+offv;
    } else {
      sorder[(size_t)b*1536 + r] = 0;
      float* pp = snb + ((size_t)b*1536 + r)*4;
      pp[0]=pp[1]=pp[2]=pp[3]=0.f;
    }
  }
}

// ---------- 5b. NMS: IoU suppression bitmask matrix ----------
__global__ __launch_bounds__(256) void nms_mask(
    const float* __restrict__ snb, unsigned long long* __restrict__ masks){
  int b = blockIdx.y;
  int i0 = blockIdx.x*64;
  __shared__ float sbx[1536][4];
  for (int t=threadIdx.x; t<1536*4; t+=256)
    sbx[t>>2][t&3] = snb[(size_t)b*1536*4 + t];
  __syncthreads();
  int il = threadIdx.x >> 2;
  int wq = threadIdx.x & 3;
  int i = i0 + il;
  float ax1=sbx[i][0], ay1=sbx[i][1], ax2=sbx[i][2], ay2=sbx[i][3];
  float aa=(ax2-ax1)*(ay2-ay1);
  #pragma unroll
  for (int wofs=0; wofs<6; ++wofs){
    int w = wq*6 + wofs;
    unsigned long long m = 0ull;
    if (i < 1500){
      for (int jj=0; jj<64; ++jj){
        int j = w*64 + jj;
        if (j > i && j < 1500){
          float bx1=sbx[j][0],by1=sbx[j][1],bx2=sbx[j][2],by2=sbx[j][3];
          float ab=(bx2-bx1)*(by2-by1);
          float lx=fmaxf(ax1,bx1), ly=fmaxf(ay1,by1);
          float rx=fminf(ax2,bx2), ry=fminf(ay2,by2);
          float iw=fmaxf(rx-lx,0.f), ih=fmaxf(ry-ly,0.f);
          float inter=iw*ih;
          if (inter/(aa+ab-inter+1e-9f) > 0.7f) m |= (1ull<<jj);
        }
      }
    }
    masks[((size_t)b*1536 + i)*24 + w] = m;
  }
}

// ---------- 5c. NMS: serial bitmask scan + final top-512 gather ----------
__global__ __launch_bounds__(1024) void nms_scan_final(
    const unsigned long long* __restrict__ masks, const int* __restrict__ sorder,
    const float* __restrict__ lvl_boxes, const float* __restrict__ lvl_scores,
    float* __restrict__ props){
  int b = blockIdx.x, tid = threadIdx.x;
  __shared__ unsigned long long cm[128][24];
  __shared__ volatile unsigned long long keepw[24];
  __shared__ unsigned char korig[1536];
  __shared__ unsigned long long keys[2048];
  if (tid < 24) keepw[tid] = (tid==23) ? ((1ull<<28)-1ull) : ~0ull;
  for (int c=0; c<12; ++c){
    __syncthreads();
    for (int t=tid; t<128*24; t+=1024)
      cm[t/24][t%24] = masks[((size_t)b*1536 + c*128)*24 + t];
    __syncthreads();
    if (tid < 24){
      int lim = (c==11) ? 84 : 128;
      for (int il=0; il<lim; ++il){
        int i = c*128 + il;
        unsigned long long kw = keepw[i>>6];
        if ((kw>>(i&63)) & 1ull) keepw[tid] &= ~cm[il][tid];
      }
    }
  }
  __syncthreads();
  for (int r=tid; r<1500; r+=1024){
    unsigned long long kw = keepw[r>>6];
    korig[sorder[(size_t)b*1536 + r]] = (unsigned char)((kw>>(r&63)) & 1ull);
  }
  __syncthreads();
  const float* ls = lvl_scores + (size_t)b*1500;
  const float* lb = lvl_boxes + (size_t)b*1500*4;
  for (int i=tid;i<2048;i+=1024){
    if (i<1500){
      float s = korig[i] ? ls[i] : -1e9f;
      keys[i] = ((unsigned long long)fkey(s)<<32)|(uint32_t)(~(uint32_t)i);
    } else keys[i]=0ull;
  }
  __syncthreads();
  bitonic_desc(keys, 2048, tid, 1024);
  for (int j=tid;j<512;j+=1024){
    int idx = (int)(~(uint32_t)keys[j]);
    float* pp = props + ((size_t)b*512 + j)*4;
    pp[0]=lb[idx*4+0]; pp[1]=lb[idx*4+1]; pp[2]=lb[idx*4+2]; pp[3]=lb[idx*4+3];
  }
}

// ---------- 6. ROI align ----------
__global__ __launch_bounds__(256) void roi_align(
    const float* __restrict__ featT, const float* __restrict__ props,
    float* __restrict__ roiX){
  int blk = blockIdx.x;
  int b = blk >> 9, n = blk & 511;
  const float* box = props + ((size_t)b*512 + n)*4;
  float x1=box[0], y1=box[1], x2=box[2], y2=box[3];
  float area = fmaxf(x2-x1,0.f)*fmaxf(y2-y1,0.f);
  float kf = floorf(4.0f + log2f(sqrtf(area)/224.0f + 1e-6f));
  kf = fminf(fmaxf(kf, 3.f), 5.f);
  int lvl = (int)kf - 3;
  const int Wl[3] = {100,50,25};
  const int posOff[3] = {0,10000,12500};
  const float strid[3] = {8.f,16.f,32.f};
  float scl = 1.0f/strid[lvl];
  float hw = (float)Wl[lvl];
  float rx1 = x1*scl, ry1 = y1*scl;
  float rw = fmaxf(x2*scl - rx1, 1.0f), rh = fmaxf(y2*scl - ry1, 1.0f);
  float bw = rw/7.0f, bh = rh/7.0f;
  __shared__ int sIdx[196][4];
  __shared__ float sW[196][4];
  int t = threadIdx.x;
  if (t < 196){
    int bin = t>>2, s = t&3;
    int py = bin/7, px = bin - py*7;
    int sy = s>>1, sx = s&1;
    float sgy = ((float)sy + 0.5f)*0.5f, sgx = ((float)sx + 0.5f)*0.5f;
    float Y = ry1 + ((float)py + sgy)*bh;
    float X = rx1 + ((float)px + sgx)*bw;
    Y = fminf(fmaxf(Y,0.f), hw-1.0f);
    X = fminf(fmaxf(X,0.f), hw-1.0f);
    float y0 = floorf(Y), x0 = floorf(X);
    float ly = Y-y0, lx = X-x0;
    int y0i=(int)y0, x0i=(int)x0;
    int hi = Wl[lvl]-1;
    int y1i = (y0i+1<hi)?(y0i+1):hi;
    int x1i = (x0i+1<hi)?(x0i+1):hi;
    int W = Wl[lvl];
    int base = b*13125 + posOff[lvl];
    sIdx[t][0] = (base + y0i*W + x0i)*256;
    sIdx[t][1] = (base + y0i*W + x1i)*256;
    sIdx[t][2] = (base + y1i*W + x0i)*256;
    sIdx[t][3] = (base + y1i*W + x1i)*256;
    sW[t][0]=(1.f-ly)*(1.f-lx); sW[t][1]=(1.f-ly)*lx;
    sW[t][2]=ly*(1.f-lx);       sW[t][3]=ly*lx;
  }
  __syncthreads();
  int c = t;
  float* orow = roiX + ((size_t)b*512 + n)*12544 + (size_t)c*49;
  for (int bin=0;bin<49;bin++){
    float acc = 0.f;
    #pragma unroll
    for (int s=0;s<4;s++){
      int tt = bin*4+s;
      acc += sW[tt][0]*featT[sIdx[tt][0]+c] + sW[tt][1]*featT[sIdx[tt][1]+c]
           + sW[tt][2]*featT[sIdx[tt][2]+c] + sW[tt][3]*featT[sIdx[tt][3]+c];
    }
    orow[bin] = acc*0.25f;
  }
}

// ---------- 7. split-K GEMM: both operands in LDS, 128x128 tile, 8x8 micro (2x2 quads) ----------
// As[k][m] (transposed store), Bs[k][n] natural. Reads are <=2-way bank aliased (free).
__global__ __launch_bounds__(256) void gemm_tile(
    const float* __restrict__ Am, const float* __restrict__ Bm,
    float* __restrict__ part, int M, int N, int K, int KC){
  __shared__ float As[16][132];
  __shared__ float Bs[16][132];
  const int tid = threadIdx.x;
  const int bn = blockIdx.x*128, bm = blockIdx.y*128, kz = blockIdx.z;
  const int k0 = kz*KC;
  const int nsteps = KC/16;
  const int tn1 = (tid & 15)*4;
  const int tm1 = ((tid >> 4) & 15)*4;
  float acc[2][2][4][4];
  #pragma unroll
  for (int qi=0;qi<2;qi++)
    #pragma unroll
    for (int qj=0;qj<2;qj++)
      #pragma unroll
      for (int i=0;i<4;i++)
        #pragma unroll
        for (int j=0;j<4;j++) acc[qi][qj][i][j]=0.f;

  const int am  = tid >> 2;        // 0..63 (+64 second half)
  const int ak4 = tid & 3;         // float4 index along k
  const int bk  = tid >> 5;        // 0..7 (+8 second half)
  const int bn4 = tid & 31;        // float4 index along n
  float4 pa0, pa1, pb0, pb1;

  // prologue
  {
    const int kb = k0;
    pa0 = *reinterpret_cast<const float4*>(&Am[(size_t)(bm+am)*K + kb + ak4*4]);
    pa1 = *reinterpret_cast<const float4*>(&Am[(size_t)(bm+am+64)*K + kb + ak4*4]);
    pb0 = *reinterpret_cast<const float4*>(&Bm[(size_t)(kb+bk)*N + bn + bn4*4]);
    pb1 = *reinterpret_cast<const float4*>(&Bm[(size_t)(kb+bk+8)*N + bn + bn4*4]);
  }
  As[ak4*4+0][am]=pa0.x; As[ak4*4+1][am]=pa0.y; As[ak4*4+2][am]=pa0.z; As[ak4*4+3][am]=pa0.w;
  As[ak4*4+0][am+64]=pa1.x; As[ak4*4+1][am+64]=pa1.y; As[ak4*4+2][am+64]=pa1.z; As[ak4*4+3][am+64]=pa1.w;
  *reinterpret_cast<float4*>(&Bs[bk][bn4*4]) = pb0;
  *reinterpret_cast<float4*>(&Bs[bk+8][bn4*4]) = pb1;
  __syncthreads();

  for (int t=0; t<nsteps; ++t){
    if (t+1 < nsteps){
      const int kb = k0 + (t+1)*16;
      pa0 = *reinterpret_cast<const float4*>(&Am[(size_t)(bm+am)*K + kb + ak4*4]);
      pa1 = *reinterpret_cast<const float4*>(&Am[(size_t)(bm+am+64)*K + kb + ak4*4]);
      pb0 = *reinterpret_cast<const float4*>(&Bm[(size_t)(kb+bk)*N + bn + bn4*4]);
      pb1 = *reinterpret_cast<const float4*>(&Bm[(size_t)(kb+bk+8)*N + bn + bn4*4]);
    }
    #pragma unroll
    for (int kk=0; kk<16; ++kk){
      float4 a0 = *reinterpret_cast<const float4*>(&As[kk][tm1]);
      float4 a1 = *reinterpret_cast<const float4*>(&As[kk][tm1+64]);
      float4 b0 = *reinterpret_cast<const float4*>(&Bs[kk][tn1]);
      float4 b1 = *reinterpret_cast<const float4*>(&Bs[kk][tn1+64]);
      float ar0[4]={a0.x,a0.y,a0.z,a0.w}, ar1[4]={a1.x,a1.y,a1.z,a1.w};
      float br0[4]={b0.x,b0.y,b0.z,b0.w}, br1[4]={b1.x,b1.y,b1.z,b1.w};
      #pragma unroll
      for (int i=0;i<4;i++)
        #pragma unroll
        for (int j=0;j<4;j++){
          acc[0][0][i][j] += ar0[i]*br0[j];
          acc[0][1][i][j] += ar0[i]*br1[j];
          acc[1][0][i][j] += ar1[i]*br0[j];
          acc[1][1][i][j] += ar1[i]*br1[j];
        }
    }
    if (t+1 < nsteps){
      __syncthreads();
      As[ak4*4+0][am]=pa0.x; As[ak4*4+1][am]=pa0.y; As[ak4*4+2][am]=pa0.z; As[ak4*4+3][am]=pa0.w;
      As[ak4*4+0][am+64]=pa1.x; As[ak4*4+1][am+64]=pa1.y; As[ak4*4+2][am+64]=pa1.z; As[ak4*4+3][am+64]=pa1.w;
      *reinterpret_cast<float4*>(&Bs[bk][bn4*4]) = pb0;
      *reinterpret_cast<float4*>(&Bs[bk+8][bn4*4]) = pb1;
      __syncthreads();
    }
  }

  float* pz = part + (size_t)kz*M*N;
  #pragma unroll
  for (int qi=0;qi<2;qi++){
    #pragma unroll
    for (int i=0;i<4;i++){
      int row = bm + tm1 + qi*64 + i;
      #pragma unroll
      for (int qj=0;qj<2;qj++){
        float4 v = make_float4(acc[qi][qj][i][0],acc[qi][qj][i][1],
                               acc[qi][qj][i][2],acc[qi][qj][i][3]);
        *reinterpret_cast<float4*>(&pz[(size_t)row*N + bn + tn1 + qj*64]) = v;
      }
    }
  }
}

// reduce SPLITK=4 partials + bias (+relu). N must be pow2.
__global__ __launch_bounds__(256) void reduce_splitk(
    const float* __restrict__ part, const float* __restrict__ bias,
    float* __restrict__ out, int MN, int Nmask, int relu){
  int i4 = (blockIdx.x*256 + threadIdx.x)*4;
  if (i4 < MN){
    float4 s0 = *reinterpret_cast<const float4*>(&part[i4]);
    float4 s1 = *reinterpret_cast<const float4*>(&part[(size_t)MN + i4]);
    float4 s2 = *reinterpret_cast<const float4*>(&part[(size_t)2*MN + i4]);
    float4 s3 = *reinterpret_cast<const float4*>(&part[(size_t)3*MN + i4]);
    float4 bb = *reinterpret_cast<const float4*>(&bias[i4 & Nmask]);
    float4 r;
    r.x = s0.x+s1.x+s2.x+s3.x+bb.x;
    r.y = s0.y+s1.y+s2.y+s3.y+bb.y;
    r.z = s0.z+s1.z+s2.z+s3.z+bb.z;
    r.w = s0.w+s1.w+s2.w+s3.w+bb.w;
    if (relu){ r.x=fmaxf(r.x,0.f); r.y=fmaxf(r.y,0.f); r.z=fmaxf(r.z,0.f); r.w=fmaxf(r.w,0.f); }
    *reinterpret_cast<float4*>(&out[i4]) = r;
  }
}

// ---------- 8. cls/box heads: wave-per-output shuffle reduce ----------
__global__ __launch_bounds__(256) void fc_heads(
    const float* __restrict__ x,
    const float* __restrict__ wcls, const float* __restrict__ bcls,
    const float* __restrict__ wbox, const float* __restrict__ bbox,
    float* __restrict__ cls, float* __restrict__ box){
  int row = blockIdx.x, tid = threadIdx.x;
  __shared__ float xs[1024];
  *reinterpret_cast<float4*>(&xs[tid*4]) =
      *reinterpret_cast<const float4*>(&x[(size_t)row*1024 + tid*4]);
  __syncthreads();
  int w = tid >> 6, lane = tid & 63;
  for (int o=w; o<10; o+=4){
    float p = 0.f;
    if (o < 2){
      for (int k=lane;k<1024;k+=64) p += xs[k]*wcls[(size_t)k*2 + o];
    } else {
      int q = o-2;
      for (int k=lane;k<1024;k+=64) p += xs[k]*wbox[(size_t)k*8 + q];
    }
    #pragma unroll
    for (int off=32; off>0; off>>=1) p += __shfl_down(p, off);
    if (lane==0){
      if (o<2) cls[(size_t)row*2 + o] = p + bcls[o];
      else     box[(size_t)row*8 + (o-2)] = p + bbox[o-2];
    }
  }
}

// ---------- 9. per-batch postprocess (bitmask NMS in LDS) ----------
__global__ __launch_bounds__(1024) void postprocess_kernel(
    const float* __restrict__ cls, const float* __restrict__ boxd,
    const float* __restrict__ props, float* __restrict__ out){
  int b = blockIdx.x, tid = threadIdx.x;
  __shared__ float pb[512][4];
  __shared__ float sraw[512];
  __shared__ float s2a[512];
  __shared__ unsigned long long keys[512];
  __shared__ unsigned short order_[512];
  __shared__ unsigned char kval[512];
  __shared__ unsigned char korig[512];
  __shared__ unsigned long long pm[512][8];
  __shared__ volatile unsigned long long kw2[8];
  if (tid < 8) kw2[tid] = ~0ull;
  if (tid < 512){
    int r = b*512 + tid;
    float c0 = cls[(size_t)r*2+0], c1 = cls[(size_t)r*2+1];
    float mx = fmaxf(c0,c1);
    float e0 = expf(c0-mx), e1 = expf(c1-mx);
    float s = e1/(e0+e1);
    const float* pr = props + (size_t)r*4;
    float x1=pr[0], y1=pr[1], x2=pr[2], y2=pr[3];
    float w = x2-x1, h = y2-y1;
    float cx = x1 + 0.5f*w, cy = y1 + 0.5f*h;
    const float* dl = boxd + (size_t)r*8 + 4;
    float dx = dl[0]/10.f, dy = dl[1]/10.f;
    float dw = fminf(dl[2]/5.f, CLIPF), dh = fminf(dl[3]/5.f, CLIPF);
    float pcx = dx*w + cx, pcy = dy*h + cy;
    float pw = expf(dw)*w, ph = expf(dh)*h;
    float bx1 = fminf(fmaxf(pcx-0.5f*pw,0.f), IMGF);
    float by1 = fminf(fmaxf(pcy-0.5f*ph,0.f), IMGF);
    float bx2 = fminf(fmaxf(pcx+0.5f*pw,0.f), IMGF);
    float by2 = fminf(fmaxf(pcy+0.5f*ph,0.f), IMGF);
    pb[tid][0]=bx1; pb[tid][1]=by1; pb[tid][2]=bx2; pb[tid][3]=by2;
    bool valid = (s > 0.05f) && (bx2-bx1 >= 1e-2f) && (by2-by1 >= 1e-2f);
    sraw[tid]=s; kval[tid] = valid ? 1 : 0;
    float sm = valid ? s : -1e9f;
    keys[tid] = ((unsigned long long)fkey(sm)<<32) | (uint32_t)(~(uint32_t)tid);
  }
  __syncthreads();
  bitonic_desc(keys, 512, tid, 1024);
  if (tid < 512) order_[tid] = (unsigned short)(~(uint32_t)keys[tid]);
  __syncthreads();
  {
    int r = tid >> 1;
    int oi = order_[r];
    float ax1=pb[oi][0],ay1=pb[oi][1],ax2=pb[oi][2],ay2=pb[oi][3];
    float aa=(ax2-ax1)*(ay2-ay1);
    #pragma unroll
    for (int wo=0; wo<4; ++wo){
      int w = (tid&1)*4 + wo;
      unsigned long long m = 0ull;
      for (int jj=0;jj<64;jj++){
        int j = w*64 + jj;
        if (j > r){
          int oj = order_[j];
          float bx1=pb[oj][0],by1=pb[oj][1],bx2=pb[oj][2],by2=pb[oj][3];
          float ab=(bx2-bx1)*(by2-by1);
          float lx=fmaxf(ax1,bx1), ly=fmaxf(ay1,by1);
          float rx=fminf(ax2,bx2), ry=fminf(ay2,by2);
          float iw=fmaxf(rx-lx,0.f), ih=fmaxf(ry-ly,0.f);
          float inter=iw*ih;
          if (inter/(aa+ab-inter+1e-9f) > 0.5f) m |= (1ull<<jj);
        }
      }
      pm[r][w] = m;
    }
  }
  __syncthreads();
  if (tid < 8){
    for (int i=0;i<512;i++){
      unsigned long long kwv = kw2[i>>6];
      if ((kwv>>(i&63)) & 1ull) kw2[tid] &= ~pm[i][tid];
    }
  }
  __syncthreads();
  if (tid < 512){
    unsigned long long kwv = kw2[tid>>6];
    korig[order_[tid]] = (unsigned char)((kwv>>(tid&63)) & 1ull);
  }
  __syncthreads();
  if (tid < 512){
    float s2 = (korig[tid] && kval[tid]) ? sraw[tid] : 0.f;
    s2a[tid] = s2;
    keys[tid] = ((unsigned long long)fkey(s2)<<32) | (uint32_t)(~(uint32_t)tid);
  }
  __syncthreads();
  bitonic_desc(keys, 512, tid, 1024);
  if (tid < 100){
    uint32_t idx = ~(uint32_t)keys[tid];
    float ts = s2a[idx];
    float ok = (ts > 0.f) ? 1.f : 0.f;
    float* op = out + ((size_t)b*100 + tid)*6;
    op[0]=pb[idx][0]*ok; op[1]=pb[idx][1]*ok;
    op[2]=pb[idx][2]*ok; op[3]=pb[idx][3]*ok;
    op[4]=ts; op[5]=ok;
  }
}

// ---------- host launch ----------
extern "C" void kernel_launch(void* const* d_in, const int* in_sizes, int n_in,
                              void* d_out, int out_size, void* d_ws, size_t ws_size,
                              hipStream_t stream){
  (void)in_sizes; (void)n_in; (void)out_size; (void)ws_size;
  const float* feat[3] = {(const float*)d_in[0], (const float*)d_in[1], (const float*)d_in[2]};
  const float* rpn_conv_w = (const float*)d_in[3];
  const float* rpn_conv_b = (const float*)d_in[4];
  const float* rpn_cls_w  = (const float*)d_in[5];
  const float* rpn_cls_b  = (const float*)d_in[6];
  const float* rpn_box_w  = (const float*)d_in[7];
  const float* rpn_box_b  = (const float*)d_in[8];
  const float* fc1_w = (const float*)d_in[9];
  const float* fc1_b = (const float*)d_in[10];
  const float* fc2_w = (const float*)d_in[11];
  const float* fc2_b = (const float*)d_in[12];
  const float* cls_w = (const float*)d_in[13];
  const float* cls_b = (const float*)d_in[14];
  const float* box_w = (const float*)d_in[15];
  const float* box_b = (const float*)d_in[16];

  float* ws = (float*)d_ws;
  // region A [0 .. 6,720,000): featT (live transpose..roi_align) / fc stage after
  float* featT = ws;
  float* fc1o  = ws;                        // 1,048,576
  float* fc2o  = ws + 1048576;              // 1,048,576
  float* clsb  = ws + 2097152;              //     2,048
  float* boxb  = ws + 2099200;              //     8,192
  float* parts = ws + 2107392;              // 4,194,304 -> ends 6,301,696
  float* props = ws + 6720000;              //     4,096
  // region C [6,724,096 ..): roiX (roi_align..fc1), earlier aliased by RPN temps
  float* roiX  = ws + 6724096;              // 12,845,056
  float* t0 = roiX;                         // 5,120,000
  float* t1 = roiX + 5120000;               // 1,280,000
  float* t2 = roiX + 6400000;               //   320,000
  float* objs       = roiX + 6720000;       //   393,750
  float* dels       = roiX + 7113750;       // 1,575,000
  float* lvl_boxes  = roiX + 8688750;       //    12,000
  float* lvl_scores = roiX + 8700750;       //     3,000
  float* nms_snb    = roiX + 8703750;       //    12,288
  int*   nms_order  = (int*)(roiX + 8716038);       //  3,072 ints
  unsigned long long* nms_masks = (unsigned long long*)(roiX + 8719110); // 147,456 floats
  float* wrp2  = roiX + 8866568;            //    20,480
  float* w2    = roiX + 8887048;            //   589,824 -> ends 9,476,872 (< 12,845,056)

  const int HWs[3]   = {10000,2500,625};
  const int lvlOff[3]= {0,150000,187500};
  const int posOff[3]= {0,10000,12500};

  repack_heads_w<<<80, 256, 0, stream>>>(rpn_cls_w, rpn_box_w, wrp2);
  repack_conv_w<<<2304, 256, 0, stream>>>(rpn_conv_w, w2);

  for (int l=0;l<3;l++){
    dim3 gt((HWs[l]+31)/32, 8, 2);
    feat_transpose<<<gt, 256, 0, stream>>>(feat[l], featT, HWs[l], posOff[l]);
  }
  conv3x3_all<<<1104, 256, 0, stream>>>(feat[0], feat[1], feat[2], w2, rpn_conv_b, t0, t1, t2);
  float* tl[3] = {t0, t1, t2};
  for (int l=0;l<3;l++){
    dim3 gh((HWs[l]+63)/64, 2);
    rpn_heads<<<gh, 256, 0, stream>>>(tl[l], wrp2, rpn_cls_b, rpn_box_b,
                                      objs, dels, HWs[l], lvlOff[l]);
  }
  rpn_topk_decode<<<dim3(3,2), 1024, 0, stream>>>(objs, dels, lvl_boxes, lvl_scores);
  nms_sort<<<2, 1024, 0, stream>>>(lvl_boxes, lvl_scores, nms_snb, nms_order);
  nms_mask<<<dim3(24,2), 256, 0, stream>>>(nms_snb, nms_masks);
  nms_scan_final<<<2, 1024, 0, stream>>>(nms_masks, nms_order, lvl_boxes, lvl_scores, props);
  roi_align<<<1024, 256, 0, stream>>>(featT, props, roiX);
  // fc1: [1024,12544] x [12544,1024], split-K=4 (KC=3136, 196 k-steps)
  gemm_tile<<<dim3(8,8,4), 256, 0, stream>>>(roiX, fc1_w, parts, 1024, 1024, 12544, 3136);
  reduce_splitk<<<1024, 256, 0, stream>>>(parts, fc1_b, fc1o, 1024*1024, 1023, 1);
  // fc2: [1024,1024] x [1024,1024], split-K=4 (KC=256, 16 k-steps)
  gemm_tile<<<dim3(8,8,4), 256, 0, stream>>>(fc1o, fc2_w, parts, 1024, 1024, 1024, 256);
  reduce_splitk<<<1024, 256, 0, stream>>>(parts, fc2_b, fc2o, 1024*1024, 1023, 1);
  fc_heads<<<1024, 256, 0, stream>>>(fc2o, cls_w, cls_b, box_w, box_b, clsb, boxb);
  postprocess_kernel<<<2, 1024, 0, stream>>>(clsb, boxb, props, (float*)d_out);
}